// Round 9
// baseline (738.198 us; speedup 1.0000x reference)
//
#include <hip/hip_runtime.h>
#include <hip/hip_bf16.h>

typedef __hip_bfloat16 bf16;
typedef __attribute__((ext_vector_type(8))) unsigned short us8;

// Problem constants
constexpr int N_ = 50000;
constexpr int E_ = 800000;
constexpr int C_ = 32;
constexpr int Z_ = 10;

// fp32 weight arena offsets (floats)
constexpr int OFF_EMB  = 0;                    // [Z][C]          320
constexpr int OFF_UPS  = 320;                  // [L][C][C]       2048
constexpr int OFF_UPV  = OFF_UPS + 2048;       // [L][C][C]       2048
constexpr int OFF_R1T  = OFF_UPV + 2048;       // [L][64][8]  (transposed)  1024
constexpr int OFF_R2   = OFF_R1T + 1024;       // [L][64][64]     8192
constexpr int OFF_R3T  = OFF_R2 + 8192;        // [L][32][5][64] (c-major) 20480
constexpr int OFF_OUTS = OFF_R3T + 20480;      // [L][C][C]       2048
constexpr int OFF_OUTV = OFF_OUTS + 2048;      // [L][C][C]       2048
constexpr int OFF_SCS  = OFF_OUTV + 2048;      // [L][Z][C][C]    20480
constexpr int OFF_SCV  = OFF_SCS + 20480;      // [L][Z][C][C]    20480
constexpr int OFF_WP   = OFF_SCV + 20480;      // [L][Z][5][C]    3200
constexpr int OFF_LINS = OFF_WP + 3200;        // [L][C][C]       2048
constexpr int OFF_LINV = OFF_LINS + 2048;      // [L][C][C]       2048
constexpr int W_TOTAL  = OFF_LINV + 2048;      // 86464

// workspace layout, in 4-byte words (within proven 56.41 MiB arena)
constexpr size_t O_CNT  = 0;                   // int: active edge count
constexpr size_t O_FLAG = 1;                   // int: 1 => float inputs are bf16
constexpr size_t O_SHZ  = 2;                   // int: 1 => shifts are NONZERO
constexpr size_t O_SPEC = 64;                  // N ints (padded 50048)
constexpr size_t O_SD   = 50112;               // 250000 u32: (src<<16)|dst, dst-sorted
constexpr size_t O_EID2 = 300112;              // 250000 int: original edge id per slot
                                               //   (consumed only when shifts nonzero)
constexpr size_t O_TAB  = 550112;              // [L=2][512][32][8] fp32 w-table, 262144
constexpr size_t O_EMBU = 812256;              // [Z][C] fp32 embup = emb@Wus0, 320 words
                                               //   ends 812576 < 850112
constexpr size_t O_POSF = 850112;              // N*3 fp32 (padded 150016)
constexpr size_t O_W    = 1000128;             // W_TOTAL fp32
constexpr size_t O_S    = 1086592;             // N*C fp32 (state s)
constexpr size_t O_VB   = 2686592;             // N*C*3 bf16 (state v, 2400000 words)
constexpr size_t O_SUB  = 5086592;             // N*C bf16   (800000 words)
constexpr size_t O_VUB  = 5886592;             // N*C*3 bf16 (2400000 words)
constexpr size_t O_SS   = 8286592;             // N*C fp32   (S accum)
constexpr size_t O_VV   = 9886592;             // N*C*3 fp32 (V accum) -> ends 14686592
constexpr size_t O_ROWP = 14686592;            // N ints (padded 50048): rowptr (destructive)

constexpr int NT_ = 512;                       // radial table points over r in [0,5]

struct ConvArgs { const void* p[13]; };

// dual-dtype input load: isb is wave-uniform => scalar branch
__device__ __forceinline__ float ldi(const void* p, int i, int isb) {
    if (isb) return (float)((const bf16*)p)[i];
    return ((const float*)p)[i];
}
__device__ __forceinline__ float b2f(unsigned short u) {   // bf16 bits -> float
    union { unsigned x; float f; } v; v.x = ((unsigned)u) << 16; return v.f;
}
// element i (0..23) of a 24-ushort row held as three us8 (i must fold to constant)
__device__ __forceinline__ float vr24(const us8 a, const us8 b, const us8 c, int i) {
    unsigned short u = (i < 8) ? a[i & 7] : (i < 16) ? b[i & 7] : c[i & 7];
    return b2f(u);
}

// ---- dtype detection on node_attrs (one-hot): word 0x00003F80 occurs only if bf16 ----
__global__ __launch_bounds__(256) void detect_kernel(const unsigned* __restrict__ a,
                                                     int* __restrict__ flag) {
    int t = threadIdx.x;
    int hit = 0;
    for (int i = t; i < 4096; i += 256) hit |= (a[i] == 0x00003F80u) ? 1 : 0;
    if (hit) atomicOr(flag, 1);
}

// ---- shifts nonzero detection (any nonzero word -> shz=1). Runs after detect. ----
__global__ __launch_bounds__(256) void shiftchk_kernel(const unsigned* __restrict__ sh,
                                                       const int* __restrict__ flag,
                                                       int* __restrict__ shz) {
    int words = (*flag) ? (E_ * 3 / 2) : (E_ * 3);
    int t = blockIdx.x * 256 + threadIdx.x;
    int hit = 0;
    for (int i = t; i < words; i += 2048 * 256) hit |= (sh[i] != 0u) ? 1 : 0;
    if (hit) atomicOr(shz, 1);
}

// ---- weight conversion (-> fp32, with R1/R3 transposes) ----
__global__ __launch_bounds__(256) void convert_kernel(ConvArgs a, const int* __restrict__ flag,
                                                      float* __restrict__ Wc) {
    int t = blockIdx.x * 256 + threadIdx.x;
    if (t >= W_TOTAL) return;
    int isb = *flag;
    int u = t;
    if (u < 320)  { Wc[OFF_EMB + u] = ldi(a.p[0], u, isb); return; }  u -= 320;
    if (u < 2048) { Wc[OFF_UPS + u] = ldi(a.p[1], u, isb); return; }  u -= 2048;
    if (u < 2048) { Wc[OFF_UPV + u] = ldi(a.p[2], u, isb); return; }  u -= 2048;
    if (u < 1024) {                       // R1 [L][8][64] -> R1T [L][64][8]
        int l = u >> 9, r = u & 511, j = r >> 3, k = r & 7;
        Wc[OFF_R1T + u] = ldi(a.p[3], l * 512 + k * 64 + j, isb); return;
    }  u -= 1024;
    if (u < 8192) { Wc[OFF_R2 + u] = ldi(a.p[4], u, isb); return; }   u -= 8192;
    if (u < 20480) {                      // R3 [L][64][160] -> R3T [L][32][5][64] (c-major)
        int l = u / 10240, r = u % 10240, c = r / 320, r2 = r % 320, p = r2 / 64, j = r2 % 64;
        Wc[OFF_R3T + u] = ldi(a.p[5], l * 10240 + j * 160 + p * 32 + c, isb); return;
    }  u -= 20480;
    if (u < 2048)  { Wc[OFF_OUTS + u] = ldi(a.p[6], u, isb);  return; } u -= 2048;
    if (u < 2048)  { Wc[OFF_OUTV + u] = ldi(a.p[7], u, isb);  return; } u -= 2048;
    if (u < 20480) { Wc[OFF_SCS  + u] = ldi(a.p[8], u, isb);  return; } u -= 20480;
    if (u < 20480) { Wc[OFF_SCV  + u] = ldi(a.p[9], u, isb);  return; } u -= 20480;
    if (u < 3200)  { Wc[OFF_WP   + u] = ldi(a.p[10], u, isb); return; } u -= 3200;
    if (u < 2048)  { Wc[OFF_LINS + u] = ldi(a.p[11], u, isb); return; } u -= 2048;
    Wc[OFF_LINV + u] = ldi(a.p[12], u, isb);
}

// ---- positions -> fp32 ----
__global__ __launch_bounds__(256) void posconv_kernel(const void* __restrict__ pos,
                                                      const int* __restrict__ flag,
                                                      float* __restrict__ posf) {
    int t = blockIdx.x * 256 + threadIdx.x;
    if (t >= N_ * 3) return;
    posf[t] = ldi(pos, t, *flag);
}

// ---- species from one-hot ----
__global__ __launch_bounds__(256) void spec_kernel(const void* __restrict__ attrs,
                                                   const int* __restrict__ flag,
                                                   int* __restrict__ spec) {
    int n = blockIdx.x * 256 + threadIdx.x;
    if (n >= N_) return;
    int isb = *flag;
    int z = 0;
    #pragma unroll
    for (int zz = 0; zz < Z_; zz++)
        if (ldi(attrs, n * Z_ + zz, isb) > 0.5f) z = zz;
    spec[n] = z;
}

// ---- embup[z][d] = sum_c emb[z][c] * Wus0[c][d]  (replaces up_kernel for l=0) ----
__global__ __launch_bounds__(320) void embup_kernel(const float* __restrict__ Wc,
                                                    float* __restrict__ embup) {
    int t = threadIdx.x;
    if (t >= 320) return;
    int z = t >> 5, d = t & 31;
    float a = 0.f;
    #pragma unroll 8
    for (int c = 0; c < 32; c++)
        a += Wc[OFF_EMB + z * 32 + c] * Wc[OFF_UPS + c * 32 + d];
    embup[t] = a;
}

// ---- s init: s = emb[spec]; su = bf16(embup[spec]); vu = 0 (v=0 at l=0) ----
__global__ __launch_bounds__(256) void sinit_kernel(const float* __restrict__ Wc,
                                                    const float* __restrict__ embup,
                                                    const int* __restrict__ spec,
                                                    float* __restrict__ s,
                                                    bf16* __restrict__ su,
                                                    bf16* __restrict__ vu) {
    int t = blockIdx.x * 256 + threadIdx.x;   // N*C threads
    int n = t >> 5, c = t & 31;
    int z = spec[n];
    s[t] = Wc[OFF_EMB + z * C_ + c];
    su[t] = __float2bfloat16(embup[z * C_ + c]);
    vu[t * 3 + 0] = __float2bfloat16(0.f);
    vu[t * 3 + 1] = __float2bfloat16(0.f);
    vu[t * 3 + 2] = __float2bfloat16(0.f);
}

__device__ __forceinline__ float silu_f(float a) {
    return a / (1.f + __expf(-a));
}

// ---- radial w-table build: tab[l][k][c][8] = (h2(r_k) @ R3T)[c][p], p in 0..4 ----
__global__ __launch_bounds__(256) void tab_kernel(const float* __restrict__ Wc,
                                                  float* __restrict__ tab) {
    __shared__ float h1s[64];
    __shared__ float h2s[64];
    int bk = blockIdx.x;               // 0..1023 = l*512 + k
    int l = bk >> 9, k = bk & 511;
    int t = threadIdx.x;
    float r = (5.0f / (float)(NT_ - 1)) * (float)k;
    float rs = fmaxf(r, 1e-9f);
    float inv = 1.0f / rs;
    float x = r * 0.2f;
    float x2 = x * x, x3 = x2 * x, x6 = x3 * x3, x7 = x6 * x, x8 = x7 * x;
    float fcv = 1.f - 28.f * x6 + 48.f * x7 - 21.f * x8;
    float scl = 0.63245553203367587f * inv * fcv;
    float ef[8];
    #pragma unroll
    for (int q = 0; q < 8; q++)
        ef[q] = scl * sinf(0.62831853071795865f * rs * (float)(q + 1));

    const float* r1  = Wc + OFF_R1T + l * 512;    // [64][8]
    const float* r2w = Wc + OFF_R2  + l * 4096;   // [64][64]
    const float* r3l = Wc + OFF_R3T + l * 10240;  // [32][5][64]
    if (t < 64) {
        float a = 0.f;
        #pragma unroll
        for (int q = 0; q < 8; q++) a += ef[q] * r1[t * 8 + q];
        h1s[t] = silu_f(a);
    }
    __syncthreads();
    if (t < 64) {
        float a = 0.f;
        for (int kk = 0; kk < 64; kk++) a += h1s[kk] * r2w[kk * 64 + t];
        h2s[t] = silu_f(a);
    }
    __syncthreads();
    if (t < 160) {
        int c = t / 5, p = t % 5;
        const float* rp = r3l + (c * 5 + p) * 64;
        float a = 0.f;
        for (int j = 0; j < 64; j++) a += h2s[j] * rp[j];
        tab[(((size_t)l * NT_ + k) * 32 + c) * 8 + p] = a;
    }
}

// ---- dst-sort build step 1: per-dst degree of ACTIVE edges (r < RCUT) ----
__global__ __launch_bounds__(256) void deg_kernel(const int* __restrict__ ei,
                                                  const float* __restrict__ posf,
                                                  const void* __restrict__ shifts,
                                                  const int* __restrict__ flag,
                                                  int* __restrict__ rp) {
    int e = blockIdx.x * 256 + threadIdx.x;
    int isb = *flag;
    int s = ei[e], d = ei[E_ + e];
    if (s < 0 || s >= N_ || d < 0 || d >= N_) return;
    float vx = posf[d * 3 + 0] - posf[s * 3 + 0] + ldi(shifts, e * 3 + 0, isb);
    float vy = posf[d * 3 + 1] - posf[s * 3 + 1] + ldi(shifts, e * 3 + 1, isb);
    float vz = posf[d * 3 + 2] - posf[s * 3 + 2] + ldi(shifts, e * 3 + 2, isb);
    if (vx * vx + vy * vy + vz * vz < 25.0f) atomicAdd(rp + d, 1);
}

// ---- step 2: in-place exclusive prefix sum over rp[0..N); writes total to cnt ----
__global__ __launch_bounds__(1024) void scan_kernel(int* __restrict__ rp,
                                                    int* __restrict__ cnt) {
    __shared__ int ps[1024];
    int t = threadIdx.x;
    constexpr int CH = (N_ + 1023) / 1024;   // 49
    int base = t * CH;
    int sum = 0;
    for (int i = 0; i < CH; i++) {
        int idx = base + i;
        if (idx < N_) sum += rp[idx];
    }
    ps[t] = sum;
    __syncthreads();
    for (int off = 1; off < 1024; off <<= 1) {
        int v = (t >= off) ? ps[t - off] : 0;
        __syncthreads();
        ps[t] += v;
        __syncthreads();
    }
    int run = (t == 0) ? 0 : ps[t - 1];
    for (int i = 0; i < CH; i++) {
        int idx = base + i;
        if (idx < N_) { int v = rp[idx]; rp[idx] = run; run += v; }
    }
    if (t == 1023) cnt[0] = ps[1023];
}

// ---- step 3: counting-sort scatter; writes packed (src<<16|dst) + edge id ----
__global__ __launch_bounds__(256) void scatter_kernel(const int* __restrict__ ei,
                                                      const float* __restrict__ posf,
                                                      const void* __restrict__ shifts,
                                                      const int* __restrict__ flag,
                                                      int* __restrict__ rp,
                                                      unsigned* __restrict__ sdArr,
                                                      int* __restrict__ eidArr) {
    int e = blockIdx.x * 256 + threadIdx.x;
    int isb = *flag;
    int s = ei[e], d = ei[E_ + e];
    if (s < 0 || s >= N_ || d < 0 || d >= N_) return;
    float vx = posf[d * 3 + 0] - posf[s * 3 + 0] + ldi(shifts, e * 3 + 0, isb);
    float vy = posf[d * 3 + 1] - posf[s * 3 + 1] + ldi(shifts, e * 3 + 1, isb);
    float vz = posf[d * 3 + 2] - posf[s * 3 + 2] + ldi(shifts, e * 3 + 2, isb);
    if (vx * vx + vy * vy + vz * vz < 25.0f) {
        int pos = atomicAdd(rp + d, 1);
        sdArr[pos] = ((unsigned)s << 16) | (unsigned)d;   // N=50000 < 2^16
        eidArr[pos] = e;
    }
}

// segmented inclusive sum over the 16 groups of a wave (stride-4 lanes).
__device__ __forceinline__ float segsum16(float v, int lane, int g, int hdv) {
    #pragma unroll
    for (int s = 1; s < 16; s <<= 1) {
        float u = __shfl(v, (lane - 4 * s) & 63, 64);
        if (g - s >= hdv) v += u;
    }
    return v;
}

// ---- fused edge kernel, 4 lanes per edge, dst-sorted slots ----
// Round-9: (a) packed (src<<16|dst) read sequentially (kills random ei/eids
// line-fetches); (b) shifts loads skipped when shz==0 (detected; benchmark
// shifts are zero) — eidArr consulted only in the nonzero fallback;
// (c) lane owns CONTIGUOUS channels 8l..8l+7: sub/vub row gathers = 4 us8
// vector loads (was 32 scalar ushorts); (d) complete-run detection via exact
// head/last flags (sd[i-1]/sd[i+1] peeks): runs fully contained in the tile
// (~85% of nodes) write S/V with plain stores, others atomic — cuts the 4x
// L2 accumulator-line bounce behind WRITE_SIZE=101MB. Full j-unroll: all
// register indices compile-time (r1/r2 scratch lesson).
__global__ __launch_bounds__(256, 4) void msg_kernel(const unsigned* __restrict__ sd,
                                                     const int* __restrict__ eidA,
                                                     const int* __restrict__ cnt,
                                                     const float* __restrict__ posf,
                                                     const void* __restrict__ shifts,
                                                     const int* __restrict__ flags,
                                                     const float* __restrict__ tab,
                                                     const bf16* __restrict__ sub,
                                                     const bf16* __restrict__ vub,
                                                     float* __restrict__ S,
                                                     float* __restrict__ V, int layer) {
    int tid = threadIdx.x;
    int lane = tid & 63;
    int waveid = tid >> 6;
    int g = lane >> 2;                 // group within wave (0..15)
    int l = lane & 3;                  // lane within group (0..3)
    int total = cnt[0];
    int base = blockIdx.x * 64 + waveid * 16;
    if (base >= total) return;         // wave-uniform early out
    int i0 = base + g;
    bool valid = (i0 < total);
    int i = valid ? i0 : (total - 1);  // clamp tail; contribution zeroed via scale
    unsigned sdv = sd[i];
    int srcn = (int)(sdv >> 16), dstn = (int)(sdv & 0xFFFFu);
    float scale = valid ? 0.0625f : 0.0f;

    // ---- exact run topology (global, via sequential peeks) ----
    bool head_ex = valid && (i == 0 || (int)(sd[i - 1] & 0xFFFFu) != dstn);
    bool last_ex = valid && (i == total - 1 || (int)(sd[i + 1] & 0xFFFFu) != dstn);
    int dstx = __shfl(dstn, (lane + 4) & 63, 64);
    bool last_wt = (g == 15) || (dstx != dstn);     // within-tile run end (writer)
    int hv = head_ex ? g + 1 : 0;                   // max-scan of exact head pos+1
    #pragma unroll
    for (int s2 = 1; s2 < 16; s2 <<= 1) {
        int o = __shfl(hv, (lane - 4 * s2) & 63, 64);
        if (g >= s2) hv = max(hv, o);
    }
    int hdv = (hv > 0) ? hv - 1 : 0;
    bool complete = last_ex && (hv > 0);            // run fully inside this tile

    // ---- row gathers: lane owns contiguous channels 8l..8l+7 ----
    us8 sraw = *(const us8*)((const unsigned short*)sub + (size_t)srcn * 32 + 8 * l);
    const unsigned short* vrow = (const unsigned short*)vub + (size_t)srcn * 96 + 24 * l;
    us8 vraw0 = *(const us8*)(vrow);
    us8 vraw1 = *(const us8*)(vrow + 8);
    us8 vraw2 = *(const us8*)(vrow + 16);

    float vx = posf[dstn * 3 + 0] - posf[srcn * 3 + 0];
    float vy = posf[dstn * 3 + 1] - posf[srcn * 3 + 1];
    float vz = posf[dstn * 3 + 2] - posf[srcn * 3 + 2];
    if (flags[O_SHZ]) {                // shifts nonzero: rare fallback path
        int isb = flags[O_FLAG];
        int e = eidA[i];
        vx += ldi(shifts, e * 3 + 0, isb);
        vy += ldi(shifts, e * 3 + 1, isb);
        vz += ldi(shifts, e * 3 + 2, isb);
    }
    float r2 = vx * vx + vy * vy + vz * vz;
    float r = sqrtf(r2);
    float rs = fmaxf(r, 1e-9f);
    float inv = 1.0f / rs;
    float Yx = vx * inv, Yy = vy * inv, Yz = vz * inv;

    // table coordinates: r in [0,5) -> k0 in [0,510], frac f
    float tpos = r * ((float)(NT_ - 1) / 5.0f);
    int k0 = min((int)tpos, NT_ - 2);
    float f = tpos - (float)k0;
    const float* t0 = tab + ((size_t)layer * NT_ + k0) * 256 + 64 * l;  // ch 8l base
    const float* t1 = t0 + 256;

    float* Sd = S + (size_t)dstn * 32 + 8 * l;
    float* Vd = V + (size_t)dstn * 96 + 24 * l;

    #pragma unroll
    for (int j = 0; j < 8; j++) {      // channel c = 8l + j; all indices constant
        float4 wa = *(const float4*)(t0 + j * 8);
        float  wa4 = (t0 + j * 8)[4];
        float4 wb = *(const float4*)(t1 + j * 8);
        float  wb4 = (t1 + j * 8)[4];
        float w0 = wa.x + f * (wb.x - wa.x);
        float w1 = wa.y + f * (wb.y - wa.y);
        float w2 = wa.z + f * (wb.z - wa.z);
        float w3 = wa.w + f * (wb.w - wa.w);
        float w4 = wa4 + f * (wb4 - wa4);

        float ss  = b2f(sraw[j]);
        float vvx = vr24(vraw0, vraw1, vraw2, j * 3 + 0);
        float vvy = vr24(vraw0, vraw1, vraw2, j * 3 + 1);
        float vvz = vr24(vraw0, vraw1, vraw2, j * 3 + 2);
        float dt = vvx * Yx + vvy * Yy + vvz * Yz;
        float cx = vvy * Yz - vvz * Yy;
        float cy = vvz * Yx - vvx * Yz;
        float cz = vvx * Yy - vvy * Yx;
        float ms = (w0 * ss + w3 * dt) * scale;
        float mx = (w1 * ss * Yx + w2 * vvx + w4 * cx) * scale;
        float my = (w1 * ss * Yy + w2 * vvy + w4 * cy) * scale;
        float mz = (w1 * ss * Yz + w2 * vvz + w4 * cz) * scale;

        ms = segsum16(ms, lane, g, hdv);
        mx = segsum16(mx, lane, g, hdv);
        my = segsum16(my, lane, g, hdv);
        mz = segsum16(mz, lane, g, hdv);
        if (last_wt) {
            if (complete) {            // run fully in-tile: plain stores
                Sd[j] = ms;
                Vd[j * 3 + 0] = mx;
                Vd[j * 3 + 1] = my;
                Vd[j * 3 + 2] = mz;
            } else {                   // split across tiles: atomic partials
                atomicAdd(Sd + j, ms);
                atomicAdd(Vd + j * 3 + 0, mx);
                atomicAdd(Vd + j * 3 + 1, my);
                atomicAdd(Vd + j * 3 + 2, mz);
            }
        }
    }
}

// ---- per-node post: out/skip/product/linear, writes invariants + new s,v in-place.
// When fuse!=0 also computes next layer's "up" (su/vu) from the fresh s,v. ----
__global__ __launch_bounds__(256) void post_kernel(const float* __restrict__ Wc,
                                                   const float* __restrict__ Sb,
                                                   const float* __restrict__ Vb,
                                                   float* __restrict__ s,
                                                   bf16* __restrict__ vbst,
                                                   const int* __restrict__ spec,
                                                   float* __restrict__ out,
                                                   bf16* __restrict__ su,
                                                   bf16* __restrict__ vu,
                                                   int fuse, int layer) {
    __shared__ float A_s[8][32];
    __shared__ float A_v[8][96];
    __shared__ float B_s[8][32];
    __shared__ float B_v[8][96];
    int tid = threadIdx.x;
    int nl = tid >> 5, d = tid & 31;
    int n = blockIdx.x * 8 + nl;
    A_s[nl][d]      = Sb[n * 32 + d];
    A_v[nl][d]      = Vb[n * 96 + d];
    A_v[nl][d + 32] = Vb[n * 96 + d + 32];
    A_v[nl][d + 64] = Vb[n * 96 + d + 64];
    B_s[nl][d]      = s[n * 32 + d];
    B_v[nl][d]      = (float)vbst[n * 96 + d];
    B_v[nl][d + 32] = (float)vbst[n * 96 + d + 32];
    B_v[nl][d + 64] = (float)vbst[n * 96 + d + 64];
    __syncthreads();

    int z = spec[n];
    const float* wos = Wc + OFF_OUTS + layer * 1024;
    const float* wov = Wc + OFF_OUTV + layer * 1024;
    const float* wss = Wc + OFF_SCS + (layer * Z_ + z) * 1024;
    const float* wsv = Wc + OFF_SCV + (layer * Z_ + z) * 1024;
    float s2 = 0.f, v20 = 0.f, v21 = 0.f, v22 = 0.f;
    float scs = 0.f, scv0 = 0.f, scv1 = 0.f, scv2 = 0.f;
    #pragma unroll 8
    for (int c = 0; c < 32; c++) {
        float wo = wos[c * 32 + d], wv = wov[c * 32 + d];
        float wa = wss[c * 32 + d], wb = wsv[c * 32 + d];
        s2  += A_s[nl][c] * wo;
        v20 += A_v[nl][c * 3 + 0] * wv;
        v21 += A_v[nl][c * 3 + 1] * wv;
        v22 += A_v[nl][c * 3 + 2] * wv;
        scs  += B_s[nl][c] * wa;
        scv0 += B_v[nl][c * 3 + 0] * wb;
        scv1 += B_v[nl][c * 3 + 1] * wb;
        scv2 += B_v[nl][c * 3 + 2] * wb;
    }
    const float* wp = Wc + OFF_WP + (layer * Z_ + z) * 160;
    float we0 = wp[d], we1 = wp[32 + d], we2 = wp[64 + d], we3 = wp[96 + d], we4 = wp[128 + d];
    float ps = we0 * s2 + we1 * s2 * s2 + we2 * (v20 * v20 + v21 * v21 + v22 * v22);
    float pv0 = we3 * v20 + we4 * s2 * v20;
    float pv1 = we3 * v21 + we4 * s2 * v21;
    float pv2 = we3 * v22 + we4 * s2 * v22;
    __syncthreads();
    A_s[nl][d] = ps;
    A_v[nl][d * 3 + 0] = pv0;
    A_v[nl][d * 3 + 1] = pv1;
    A_v[nl][d * 3 + 2] = pv2;
    __syncthreads();
    const float* wls = Wc + OFF_LINS + layer * 1024;
    const float* wlv = Wc + OFF_LINV + layer * 1024;
    float sn = scs, vn0 = scv0, vn1 = scv1, vn2 = scv2;
    #pragma unroll 8
    for (int c = 0; c < 32; c++) {
        float wl = wls[c * 32 + d], w2_ = wlv[c * 32 + d];
        sn  += A_s[nl][c] * wl;
        vn0 += A_v[nl][c * 3 + 0] * w2_;
        vn1 += A_v[nl][c * 3 + 1] * w2_;
        vn2 += A_v[nl][c * 3 + 2] * w2_;
    }
    s[n * 32 + d] = sn;
    out[(size_t)n * 64 + layer * 32 + d] = sn;   // fp32 output (verified round 5)
    vbst[n * 96 + d * 3 + 0] = __float2bfloat16(vn0);
    vbst[n * 96 + d * 3 + 1] = __float2bfloat16(vn1);
    vbst[n * 96 + d * 3 + 2] = __float2bfloat16(vn2);

    if (fuse) {
        __syncthreads();
        B_s[nl][d]         = sn;
        B_v[nl][d * 3 + 0] = vn0;
        B_v[nl][d * 3 + 1] = vn1;
        B_v[nl][d * 3 + 2] = vn2;
        __syncthreads();
        const float* wus = Wc + OFF_UPS + (layer + 1) * 1024;
        const float* wuv = Wc + OFF_UPV + (layer + 1) * 1024;
        float a0 = 0.f, b0 = 0.f, b1 = 0.f, b2 = 0.f;
        #pragma unroll 8
        for (int c = 0; c < 32; c++) {
            float wS = wus[c * 32 + d], wV = wuv[c * 32 + d];
            a0 += B_s[nl][c] * wS;
            b0 += B_v[nl][c * 3 + 0] * wV;
            b1 += B_v[nl][c * 3 + 1] * wV;
            b2 += B_v[nl][c * 3 + 2] * wV;
        }
        su[n * 32 + d] = __float2bfloat16(a0);
        vu[n * 96 + d * 3 + 0] = __float2bfloat16(b0);
        vu[n * 96 + d * 3 + 1] = __float2bfloat16(b1);
        vu[n * 96 + d * 3 + 2] = __float2bfloat16(b2);
    }
}

// Host-side: resolve input pointers by element count (robust to harness input
// ordering). Greedy first-unused match preserves relative order within equal
// sizes, so if the harness order == reference dict order this is the identity.
static void resolve_inputs(const int* in_sizes, int n_in, int idx[17]) {
    const int want[17] = {150000, 500000, 2400000, 320, 2048, 2048, 1024, 8192,
                          20480, 2048, 2048, 20480, 20480, 3200, 2048, 2048, 1600000};
    for (int k = 0; k < 17; k++) idx[k] = k;   // default identity
    if (!in_sizes || n_in < 17) return;
    bool used[64];
    for (int i = 0; i < 64; i++) used[i] = false;
    int tmp[17];
    for (int k = 0; k < 17; k++) {
        int found = -1;
        for (int i = 0; i < n_in && i < 64; i++) {
            if (!used[i] && in_sizes[i] == want[k]) { found = i; break; }
        }
        if (found < 0) return;               // sizes don't match expectation: keep identity
        used[found] = true;
        tmp[k] = found;
    }
    for (int k = 0; k < 17; k++) idx[k] = tmp[k];
}

extern "C" void kernel_launch(void* const* d_in, const int* in_sizes, int n_in,
                              void* d_out, int out_size, void* d_ws, size_t ws_size,
                              hipStream_t stream) {
    (void)out_size; (void)ws_size;
    int idx[17];
    resolve_inputs(in_sizes, n_in, idx);

    const void* pos    = d_in[idx[0]];
    const void* attrs  = d_in[idx[1]];
    const void* shifts = d_in[idx[2]];
    const int*  ei     = (const int*)d_in[idx[16]];
    float* out = (float*)d_out;

    int*   I = (int*)d_ws;
    float* W = (float*)d_ws;

    hipMemsetAsync(I, 0, 64 * sizeof(int), stream);                             // cnt + flags
    hipMemsetAsync(I + O_ROWP, 0, 50048 * sizeof(int), stream);                 // degrees
    hipMemsetAsync(W + O_VB, 0, (size_t)N_ * C_ * 3 * sizeof(bf16), stream);    // v state = 0

    detect_kernel<<<1, 256, 0, stream>>>((const unsigned*)attrs, I + O_FLAG);
    shiftchk_kernel<<<2048, 256, 0, stream>>>((const unsigned*)shifts, I + O_FLAG, I + O_SHZ);

    ConvArgs ca;
    for (int k = 0; k < 13; k++) ca.p[k] = d_in[idx[3 + k]];
    convert_kernel<<<(W_TOTAL + 255) / 256, 256, 0, stream>>>(ca, I + O_FLAG, W + O_W);
    posconv_kernel<<<(N_ * 3 + 255) / 256, 256, 0, stream>>>(pos, I + O_FLAG, W + O_POSF);
    spec_kernel<<<(N_ + 255) / 256, 256, 0, stream>>>(attrs, I + O_FLAG, I + O_SPEC);
    embup_kernel<<<1, 320, 0, stream>>>(W + O_W, W + O_EMBU);
    sinit_kernel<<<(N_ * C_) / 256, 256, 0, stream>>>(W + O_W, W + O_EMBU, I + O_SPEC,
                                                      W + O_S, (bf16*)(W + O_SUB),
                                                      (bf16*)(W + O_VUB));

    // radial w-table (both layers; needs converted weights)
    tab_kernel<<<2 * NT_, 256, 0, stream>>>(W + O_W, W + O_TAB);

    // one-time dst-sorted active-edge list (counting sort; graph static across layers)
    deg_kernel<<<E_ / 256, 256, 0, stream>>>(ei, W + O_POSF, shifts, I + O_FLAG, I + O_ROWP);
    scan_kernel<<<1, 1024, 0, stream>>>(I + O_ROWP, I + O_CNT);
    scatter_kernel<<<E_ / 256, 256, 0, stream>>>(ei, W + O_POSF, shifts, I + O_FLAG,
                                                 I + O_ROWP, (unsigned*)(I + O_SD),
                                                 I + O_EID2);

    for (int l = 0; l < 2; l++) {
        hipMemsetAsync(W + O_SS, 0, (size_t)N_ * C_ * 4 * sizeof(float), stream);  // SS+VV
        msg_kernel<<<(E_ + 63) / 64, 256, 0, stream>>>((const unsigned*)(I + O_SD),
                                                       I + O_EID2, I + O_CNT,
                                                       W + O_POSF, shifts, I,
                                                       W + O_TAB,
                                                       (const bf16*)(W + O_SUB),
                                                       (const bf16*)(W + O_VUB),
                                                       W + O_SS, W + O_VV, l);
        post_kernel<<<N_ / 8, 256, 0, stream>>>(W + O_W, W + O_SS, W + O_VV,
                                                W + O_S, (bf16*)(W + O_VB),
                                                I + O_SPEC, out,
                                                (bf16*)(W + O_SUB), (bf16*)(W + O_VUB),
                                                (l == 0) ? 1 : 0, l);
    }
}

// Round 10
// 565.661 us; speedup vs baseline: 1.3050x; 1.3050x over previous
//
#include <hip/hip_runtime.h>
#include <hip/hip_bf16.h>

typedef __hip_bfloat16 bf16;

// Problem constants
constexpr int N_ = 50000;
constexpr int E_ = 800000;
constexpr int C_ = 32;
constexpr int Z_ = 10;

// fp32 weight arena offsets (floats)
constexpr int OFF_EMB  = 0;                    // [Z][C]          320
constexpr int OFF_UPS  = 320;                  // [L][C][C]       2048
constexpr int OFF_UPV  = OFF_UPS + 2048;       // [L][C][C]       2048
constexpr int OFF_R1T  = OFF_UPV + 2048;       // [L][64][8]  (transposed)  1024
constexpr int OFF_R2   = OFF_R1T + 1024;       // [L][64][64]     8192
constexpr int OFF_R3T  = OFF_R2 + 8192;        // [L][32][5][64] (c-major) 20480
constexpr int OFF_OUTS = OFF_R3T + 20480;      // [L][C][C]       2048
constexpr int OFF_OUTV = OFF_OUTS + 2048;      // [L][C][C]       2048
constexpr int OFF_SCS  = OFF_OUTV + 2048;      // [L][Z][C][C]    20480
constexpr int OFF_SCV  = OFF_SCS + 20480;      // [L][Z][C][C]    20480
constexpr int OFF_WP   = OFF_SCV + 20480;      // [L][Z][5][C]    3200
constexpr int OFF_LINS = OFF_WP + 3200;        // [L][C][C]       2048
constexpr int OFF_LINV = OFF_LINS + 2048;      // [L][C][C]       2048
constexpr int W_TOTAL  = OFF_LINV + 2048;      // 86464

// workspace layout, in 4-byte words (within proven 56.41 MiB arena)
constexpr size_t O_CNT  = 0;                   // int: active edge count
constexpr size_t O_FLAG = 1;                   // int: 1 => float inputs are bf16
constexpr size_t O_SHZ  = 2;                   // int: 1 => shifts are NONZERO
constexpr size_t O_SPEC = 64;                  // N ints (padded 50048)
constexpr size_t O_SD   = 50112;               // 250000 u32: (src<<16)|dst, dst-sorted
constexpr size_t O_EID2 = 300112;              // 250000 int: original edge id per slot
                                               //   (consumed only when shifts nonzero)
constexpr size_t O_TAB  = 550112;              // [L=2][512][32][8] fp32 w-table, 262144
constexpr size_t O_EMBU = 812256;              // [Z][C] fp32 embup = emb@Wus0, 320 words
constexpr size_t O_POSF = 850112;              // N*3 fp32 (padded 150016)
constexpr size_t O_W    = 1000128;             // W_TOTAL fp32
constexpr size_t O_S    = 1086592;             // N*C fp32 (state s)
constexpr size_t O_VB   = 2686592;             // N*C*3 bf16 (state v, 2400000 words)
constexpr size_t O_SUB  = 5086592;             // N*C bf16   (800000 words)
constexpr size_t O_VUB  = 5886592;             // N*C*3 bf16 (2400000 words)
constexpr size_t O_SS   = 8286592;             // N*C fp32   (S accum)
constexpr size_t O_VV   = 9886592;             // N*C*3 fp32 (V accum) -> ends 14686592
constexpr size_t O_ROWP = 14686592;            // N ints (padded 50048): rowptr (destructive)

constexpr int NT_ = 512;                       // radial table points over r in [0,5]

struct ConvArgs { const void* p[13]; };

// dual-dtype input load: isb is wave-uniform => scalar branch
__device__ __forceinline__ float ldi(const void* p, int i, int isb) {
    if (isb) return (float)((const bf16*)p)[i];
    return ((const float*)p)[i];
}
__device__ __forceinline__ float b2f(unsigned short u) {   // bf16 bits -> float
    union { unsigned x; float f; } v; v.x = ((unsigned)u) << 16; return v.f;
}

// ---- dtype detection on node_attrs (one-hot): word 0x00003F80 occurs only if bf16 ----
__global__ __launch_bounds__(256) void detect_kernel(const unsigned* __restrict__ a,
                                                     int* __restrict__ flag) {
    int t = threadIdx.x;
    int hit = 0;
    for (int i = t; i < 4096; i += 256) hit |= (a[i] == 0x00003F80u) ? 1 : 0;
    if (hit) atomicOr(flag, 1);
}

// ---- shifts nonzero detection (any nonzero word -> shz=1). Runs after detect. ----
__global__ __launch_bounds__(256) void shiftchk_kernel(const unsigned* __restrict__ sh,
                                                       const int* __restrict__ flag,
                                                       int* __restrict__ shz) {
    int words = (*flag) ? (E_ * 3 / 2) : (E_ * 3);
    int t = blockIdx.x * 256 + threadIdx.x;
    int hit = 0;
    for (int i = t; i < words; i += 2048 * 256) hit |= (sh[i] != 0u) ? 1 : 0;
    if (hit) atomicOr(shz, 1);
}

// ---- weight conversion (-> fp32, with R1/R3 transposes) ----
__global__ __launch_bounds__(256) void convert_kernel(ConvArgs a, const int* __restrict__ flag,
                                                      float* __restrict__ Wc) {
    int t = blockIdx.x * 256 + threadIdx.x;
    if (t >= W_TOTAL) return;
    int isb = *flag;
    int u = t;
    if (u < 320)  { Wc[OFF_EMB + u] = ldi(a.p[0], u, isb); return; }  u -= 320;
    if (u < 2048) { Wc[OFF_UPS + u] = ldi(a.p[1], u, isb); return; }  u -= 2048;
    if (u < 2048) { Wc[OFF_UPV + u] = ldi(a.p[2], u, isb); return; }  u -= 2048;
    if (u < 1024) {                       // R1 [L][8][64] -> R1T [L][64][8]
        int l = u >> 9, r = u & 511, j = r >> 3, k = r & 7;
        Wc[OFF_R1T + u] = ldi(a.p[3], l * 512 + k * 64 + j, isb); return;
    }  u -= 1024;
    if (u < 8192) { Wc[OFF_R2 + u] = ldi(a.p[4], u, isb); return; }   u -= 8192;
    if (u < 20480) {                      // R3 [L][64][160] -> R3T [L][32][5][64] (c-major)
        int l = u / 10240, r = u % 10240, c = r / 320, r2 = r % 320, p = r2 / 64, j = r2 % 64;
        Wc[OFF_R3T + u] = ldi(a.p[5], l * 10240 + j * 160 + p * 32 + c, isb); return;
    }  u -= 20480;
    if (u < 2048)  { Wc[OFF_OUTS + u] = ldi(a.p[6], u, isb);  return; } u -= 2048;
    if (u < 2048)  { Wc[OFF_OUTV + u] = ldi(a.p[7], u, isb);  return; } u -= 2048;
    if (u < 20480) { Wc[OFF_SCS  + u] = ldi(a.p[8], u, isb);  return; } u -= 20480;
    if (u < 20480) { Wc[OFF_SCV  + u] = ldi(a.p[9], u, isb);  return; } u -= 20480;
    if (u < 3200)  { Wc[OFF_WP   + u] = ldi(a.p[10], u, isb); return; } u -= 3200;
    if (u < 2048)  { Wc[OFF_LINS + u] = ldi(a.p[11], u, isb); return; } u -= 2048;
    Wc[OFF_LINV + u] = ldi(a.p[12], u, isb);
}

// ---- positions -> fp32 ----
__global__ __launch_bounds__(256) void posconv_kernel(const void* __restrict__ pos,
                                                      const int* __restrict__ flag,
                                                      float* __restrict__ posf) {
    int t = blockIdx.x * 256 + threadIdx.x;
    if (t >= N_ * 3) return;
    posf[t] = ldi(pos, t, *flag);
}

// ---- species from one-hot ----
__global__ __launch_bounds__(256) void spec_kernel(const void* __restrict__ attrs,
                                                   const int* __restrict__ flag,
                                                   int* __restrict__ spec) {
    int n = blockIdx.x * 256 + threadIdx.x;
    if (n >= N_) return;
    int isb = *flag;
    int z = 0;
    #pragma unroll
    for (int zz = 0; zz < Z_; zz++)
        if (ldi(attrs, n * Z_ + zz, isb) > 0.5f) z = zz;
    spec[n] = z;
}

// ---- embup[z][d] = sum_c emb[z][c] * Wus0[c][d]  (replaces up_kernel for l=0) ----
__global__ __launch_bounds__(320) void embup_kernel(const float* __restrict__ Wc,
                                                    float* __restrict__ embup) {
    int t = threadIdx.x;
    if (t >= 320) return;
    int z = t >> 5, d = t & 31;
    float a = 0.f;
    #pragma unroll 8
    for (int c = 0; c < 32; c++)
        a += Wc[OFF_EMB + z * 32 + c] * Wc[OFF_UPS + c * 32 + d];
    embup[t] = a;
}

// ---- s init: s = emb[spec]; su = bf16(embup[spec]); vu = 0 (v=0 at l=0) ----
__global__ __launch_bounds__(256) void sinit_kernel(const float* __restrict__ Wc,
                                                    const float* __restrict__ embup,
                                                    const int* __restrict__ spec,
                                                    float* __restrict__ s,
                                                    bf16* __restrict__ su,
                                                    bf16* __restrict__ vu) {
    int t = blockIdx.x * 256 + threadIdx.x;   // N*C threads
    int n = t >> 5, c = t & 31;
    int z = spec[n];
    s[t] = Wc[OFF_EMB + z * C_ + c];
    su[t] = __float2bfloat16(embup[z * C_ + c]);
    vu[t * 3 + 0] = __float2bfloat16(0.f);
    vu[t * 3 + 1] = __float2bfloat16(0.f);
    vu[t * 3 + 2] = __float2bfloat16(0.f);
}

__device__ __forceinline__ float silu_f(float a) {
    return a / (1.f + __expf(-a));
}

// ---- radial w-table build: tab[l][k][c][8] = (h2(r_k) @ R3T)[c][p], p in 0..4 ----
__global__ __launch_bounds__(256) void tab_kernel(const float* __restrict__ Wc,
                                                  float* __restrict__ tab) {
    __shared__ float h1s[64];
    __shared__ float h2s[64];
    int bk = blockIdx.x;               // 0..1023 = l*512 + k
    int l = bk >> 9, k = bk & 511;
    int t = threadIdx.x;
    float r = (5.0f / (float)(NT_ - 1)) * (float)k;
    float rs = fmaxf(r, 1e-9f);
    float inv = 1.0f / rs;
    float x = r * 0.2f;
    float x2 = x * x, x3 = x2 * x, x6 = x3 * x3, x7 = x6 * x, x8 = x7 * x;
    float fcv = 1.f - 28.f * x6 + 48.f * x7 - 21.f * x8;
    float scl = 0.63245553203367587f * inv * fcv;
    float ef[8];
    #pragma unroll
    for (int q = 0; q < 8; q++)
        ef[q] = scl * sinf(0.62831853071795865f * rs * (float)(q + 1));

    const float* r1  = Wc + OFF_R1T + l * 512;    // [64][8]
    const float* r2w = Wc + OFF_R2  + l * 4096;   // [64][64]
    const float* r3l = Wc + OFF_R3T + l * 10240;  // [32][5][64]
    if (t < 64) {
        float a = 0.f;
        #pragma unroll
        for (int q = 0; q < 8; q++) a += ef[q] * r1[t * 8 + q];
        h1s[t] = silu_f(a);
    }
    __syncthreads();
    if (t < 64) {
        float a = 0.f;
        for (int kk = 0; kk < 64; kk++) a += h1s[kk] * r2w[kk * 64 + t];
        h2s[t] = silu_f(a);
    }
    __syncthreads();
    if (t < 160) {
        int c = t / 5, p = t % 5;
        const float* rp = r3l + (c * 5 + p) * 64;
        float a = 0.f;
        for (int j = 0; j < 64; j++) a += h2s[j] * rp[j];
        tab[(((size_t)l * NT_ + k) * 32 + c) * 8 + p] = a;
    }
}

// ---- dst-sort build step 1: per-dst degree of ACTIVE edges (r < RCUT) ----
__global__ __launch_bounds__(256) void deg_kernel(const int* __restrict__ ei,
                                                  const float* __restrict__ posf,
                                                  const void* __restrict__ shifts,
                                                  const int* __restrict__ flag,
                                                  int* __restrict__ rp) {
    int e = blockIdx.x * 256 + threadIdx.x;
    int isb = *flag;
    int s = ei[e], d = ei[E_ + e];
    if (s < 0 || s >= N_ || d < 0 || d >= N_) return;
    float vx = posf[d * 3 + 0] - posf[s * 3 + 0] + ldi(shifts, e * 3 + 0, isb);
    float vy = posf[d * 3 + 1] - posf[s * 3 + 1] + ldi(shifts, e * 3 + 1, isb);
    float vz = posf[d * 3 + 2] - posf[s * 3 + 2] + ldi(shifts, e * 3 + 2, isb);
    if (vx * vx + vy * vy + vz * vz < 25.0f) atomicAdd(rp + d, 1);
}

// ---- step 2: in-place exclusive prefix sum over rp[0..N); writes total to cnt ----
__global__ __launch_bounds__(1024) void scan_kernel(int* __restrict__ rp,
                                                    int* __restrict__ cnt) {
    __shared__ int ps[1024];
    int t = threadIdx.x;
    constexpr int CH = (N_ + 1023) / 1024;   // 49
    int base = t * CH;
    int sum = 0;
    for (int i = 0; i < CH; i++) {
        int idx = base + i;
        if (idx < N_) sum += rp[idx];
    }
    ps[t] = sum;
    __syncthreads();
    for (int off = 1; off < 1024; off <<= 1) {
        int v = (t >= off) ? ps[t - off] : 0;
        __syncthreads();
        ps[t] += v;
        __syncthreads();
    }
    int run = (t == 0) ? 0 : ps[t - 1];
    for (int i = 0; i < CH; i++) {
        int idx = base + i;
        if (idx < N_) { int v = rp[idx]; rp[idx] = run; run += v; }
    }
    if (t == 1023) cnt[0] = ps[1023];
}

// ---- step 3: counting-sort scatter; writes packed (src<<16|dst) + edge id ----
__global__ __launch_bounds__(256) void scatter_kernel(const int* __restrict__ ei,
                                                      const float* __restrict__ posf,
                                                      const void* __restrict__ shifts,
                                                      const int* __restrict__ flag,
                                                      int* __restrict__ rp,
                                                      unsigned* __restrict__ sdArr,
                                                      int* __restrict__ eidArr) {
    int e = blockIdx.x * 256 + threadIdx.x;
    int isb = *flag;
    int s = ei[e], d = ei[E_ + e];
    if (s < 0 || s >= N_ || d < 0 || d >= N_) return;
    float vx = posf[d * 3 + 0] - posf[s * 3 + 0] + ldi(shifts, e * 3 + 0, isb);
    float vy = posf[d * 3 + 1] - posf[s * 3 + 1] + ldi(shifts, e * 3 + 1, isb);
    float vz = posf[d * 3 + 2] - posf[s * 3 + 2] + ldi(shifts, e * 3 + 2, isb);
    if (vx * vx + vy * vy + vz * vz < 25.0f) {
        int pos = atomicAdd(rp + d, 1);
        sdArr[pos] = ((unsigned)s << 16) | (unsigned)d;   // N=50000 < 2^16
        eidArr[pos] = e;
    }
}

// segmented inclusive sum over the 16 groups of a wave (stride-4 lanes).
__device__ __forceinline__ float segsum16(float v, int lane, int g, int hdv) {
    #pragma unroll
    for (int s = 1; s < 16; s <<= 1) {
        float u = __shfl(v, (lane - 4 * s) & 63, 64);
        if (g - s >= hdv) v += u;
    }
    return v;
}

// ---- fused edge kernel, 4 lanes per edge, dst-sorted slots ----
// Round-9 post-mortem: the data-path cleanup (packed sd, shz skip: FETCH
// 102->42MB) was right, but dropping the rolling prefetch for a full j-unroll
// let the allocator serialize the table-load chains (VGPR 32, VALUBusy 8.7%,
// dur 147->174us regressed), and contiguous lane channels scattered the
// group's table reads across 4 lines/iter. Round-10: restore the r8-proven
// schedule — STRIDED channels (c=4*c4+l, group reads 160B contiguous/chunk),
// '#pragma unroll 1' runtime c4 loop, ONE-AHEAD named-scalar rolling prefetch
// of table rows + state scalars — on top of r9's data path. Plus XCD-aware
// bijective block swizzle (T1): dst-sorted accumulator ranges become
// contiguous per XCD L2 (was: 25.6MB range round-robined over 8 x 4MB L2s =
// the 4x WRITE amplification).
__global__ __launch_bounds__(256, 4) void msg_kernel(const unsigned* __restrict__ sd,
                                                     const int* __restrict__ eidA,
                                                     const int* __restrict__ cnt,
                                                     const float* __restrict__ posf,
                                                     const void* __restrict__ shifts,
                                                     const int* __restrict__ flags,
                                                     const float* __restrict__ tab,
                                                     const bf16* __restrict__ sub,
                                                     const bf16* __restrict__ vub,
                                                     float* __restrict__ S,
                                                     float* __restrict__ V, int layer) {
    // XCD swizzle: within each 128-block super-tile, XCD k (= bid%8) gets a
    // CONTIGUOUS run of G=16 edge tiles. Bijective (8xG transpose); identity
    // on the tail below one super-tile.
    constexpr int G = 16, SUP = 8 * G;
    int bid = blockIdx.x;
    int nfull = ((int)gridDim.x / SUP) * SUP;
    int sbid = bid;
    if (bid < nfull) {
        int sup = bid / SUP, rr = bid % SUP;
        sbid = sup * SUP + (rr % 8) * G + (rr / 8);
    }

    int tid = threadIdx.x;
    int lane = tid & 63;
    int waveid = tid >> 6;
    int g = lane >> 2;                 // group within wave (0..15)
    int l = lane & 3;                  // lane within group (0..3)
    int total = cnt[0];
    int base = sbid * 64 + waveid * 16;
    if (base >= total) return;         // wave-uniform early out
    int i0 = base + g;
    bool valid = (i0 < total);
    int i = valid ? i0 : (total - 1);  // clamp tail; contribution zeroed via scale
    unsigned sdv = sd[i];
    int srcn = (int)(sdv >> 16), dstn = (int)(sdv & 0xFFFFu);
    float scale = valid ? 0.0625f : 0.0f;

    // ---- exact run topology (global, via sequential peeks) ----
    bool head_ex = valid && (i == 0 || (int)(sd[i - 1] & 0xFFFFu) != dstn);
    bool last_ex = valid && (i == total - 1 || (int)(sd[i + 1] & 0xFFFFu) != dstn);
    int dstx = __shfl(dstn, (lane + 4) & 63, 64);
    bool last_wt = (g == 15) || (dstx != dstn);     // within-tile run end (writer)
    int hv = head_ex ? g + 1 : 0;                   // max-scan of exact head pos+1
    #pragma unroll
    for (int s2 = 1; s2 < 16; s2 <<= 1) {
        int o = __shfl(hv, (lane - 4 * s2) & 63, 64);
        if (g >= s2) hv = max(hv, o);
    }
    int hdv = (hv > 0) ? hv - 1 : 0;
    bool complete = last_ex && (hv > 0);            // run fully inside this tile

    // strided channel base pointers (lane owns c = 4*c4 + l)
    const unsigned short* sp = (const unsigned short*)(sub + (size_t)srcn * 32 + l);
    const unsigned short* vp = (const unsigned short*)(vub + (size_t)srcn * 96 + 3 * l);
    unsigned short pf_s  = sp[0];
    unsigned short pf_v0 = vp[0], pf_v1 = vp[1], pf_v2 = vp[2];

    float vx = posf[dstn * 3 + 0] - posf[srcn * 3 + 0];
    float vy = posf[dstn * 3 + 1] - posf[srcn * 3 + 1];
    float vz = posf[dstn * 3 + 2] - posf[srcn * 3 + 2];
    if (flags[O_SHZ]) {                // shifts nonzero: rare fallback path
        int isb = flags[O_FLAG];
        int e = eidA[i];
        vx += ldi(shifts, e * 3 + 0, isb);
        vy += ldi(shifts, e * 3 + 1, isb);
        vz += ldi(shifts, e * 3 + 2, isb);
    }
    float r2 = vx * vx + vy * vy + vz * vz;
    float r = sqrtf(r2);
    float rs = fmaxf(r, 1e-9f);
    float inv = 1.0f / rs;
    float Yx = vx * inv, Yy = vy * inv, Yz = vz * inv;

    // table coordinates: r in [0,5) -> k0 in [0,510], frac f
    float tpos = r * ((float)(NT_ - 1) / 5.0f);
    int k0 = min((int)tpos, NT_ - 2);
    float f = tpos - (float)k0;
    const float* t0 = tab + ((size_t)layer * NT_ + k0) * 256;   // 32 ch * 8 floats
    const float* t1 = t0 + 256;

    // prefetch chunk 0's table rows (channel c = l)
    float4 pf_wa = *(const float4*)(t0 + l * 8);
    float  pf_wa4 = (t0 + l * 8)[4];
    float4 pf_wb = *(const float4*)(t1 + l * 8);
    float  pf_wb4 = (t1 + l * 8)[4];

    float* Sd = S + (size_t)dstn * 32;
    float* Vd = V + (size_t)dstn * 96;

    // RUNTIME c4 loop; named-scalar rolling prefetch, no dynamic register
    // indexing anywhere. c4=7 prefetch reads past the row (still inside the
    // allocated workspace arena) and is never consumed.
    #pragma unroll 1
    for (int c4 = 0; c4 < 8; c4++) {
        float ss  = b2f(pf_s);
        float vvx = b2f(pf_v0);
        float vvy = b2f(pf_v1);
        float vvz = b2f(pf_v2);
        float4 wa = pf_wa; float wa4 = pf_wa4;
        float4 wb = pf_wb; float wb4 = pf_wb4;

        // prefetch next chunk (states + table)
        pf_s  = sp[4 * c4 + 4];
        pf_v0 = vp[12 * c4 + 12];
        pf_v1 = vp[12 * c4 + 13];
        pf_v2 = vp[12 * c4 + 14];
        int noff = (4 * c4 + 4 + l) * 8;
        pf_wa = *(const float4*)(t0 + noff);
        pf_wa4 = (t0 + noff)[4];
        pf_wb = *(const float4*)(t1 + noff);
        pf_wb4 = (t1 + noff)[4];

        // lerp the 5 path weights for this lane's channel c = 4*c4 + l
        float w0 = wa.x + f * (wb.x - wa.x);
        float w1 = wa.y + f * (wb.y - wa.y);
        float w2 = wa.z + f * (wb.z - wa.z);
        float w3 = wa.w + f * (wb.w - wa.w);
        float w4 = wa4 + f * (wb4 - wa4);

        const int c = 4 * c4 + l;
        float dt = vvx * Yx + vvy * Yy + vvz * Yz;
        float cx = vvy * Yz - vvz * Yy;
        float cy = vvz * Yx - vvx * Yz;
        float cz = vvx * Yy - vvy * Yx;
        float ms = (w0 * ss + w3 * dt) * scale;
        float mx = (w1 * ss * Yx + w2 * vvx + w4 * cx) * scale;
        float my = (w1 * ss * Yy + w2 * vvy + w4 * cy) * scale;
        float mz = (w1 * ss * Yz + w2 * vvz + w4 * cz) * scale;

        // pre-sum each same-dst run; only the within-tile run-last group writes
        ms = segsum16(ms, lane, g, hdv);
        mx = segsum16(mx, lane, g, hdv);
        my = segsum16(my, lane, g, hdv);
        mz = segsum16(mz, lane, g, hdv);
        if (last_wt) {
            if (complete) {            // run fully in-tile: plain stores
                Sd[c] = ms;
                Vd[c * 3 + 0] = mx;
                Vd[c * 3 + 1] = my;
                Vd[c * 3 + 2] = mz;
            } else {                   // split across tiles: atomic partials
                atomicAdd(Sd + c, ms);
                atomicAdd(Vd + c * 3 + 0, mx);
                atomicAdd(Vd + c * 3 + 1, my);
                atomicAdd(Vd + c * 3 + 2, mz);
            }
        }
    }
}

// ---- per-node post: out/skip/product/linear, writes invariants + new s,v in-place.
// When fuse!=0 also computes next layer's "up" (su/vu) from the fresh s,v. ----
__global__ __launch_bounds__(256) void post_kernel(const float* __restrict__ Wc,
                                                   const float* __restrict__ Sb,
                                                   const float* __restrict__ Vb,
                                                   float* __restrict__ s,
                                                   bf16* __restrict__ vbst,
                                                   const int* __restrict__ spec,
                                                   float* __restrict__ out,
                                                   bf16* __restrict__ su,
                                                   bf16* __restrict__ vu,
                                                   int fuse, int layer) {
    __shared__ float A_s[8][32];
    __shared__ float A_v[8][96];
    __shared__ float B_s[8][32];
    __shared__ float B_v[8][96];
    int tid = threadIdx.x;
    int nl = tid >> 5, d = tid & 31;
    int n = blockIdx.x * 8 + nl;
    A_s[nl][d]      = Sb[n * 32 + d];
    A_v[nl][d]      = Vb[n * 96 + d];
    A_v[nl][d + 32] = Vb[n * 96 + d + 32];
    A_v[nl][d + 64] = Vb[n * 96 + d + 64];
    B_s[nl][d]      = s[n * 32 + d];
    B_v[nl][d]      = (float)vbst[n * 96 + d];
    B_v[nl][d + 32] = (float)vbst[n * 96 + d + 32];
    B_v[nl][d + 64] = (float)vbst[n * 96 + d + 64];
    __syncthreads();

    int z = spec[n];
    const float* wos = Wc + OFF_OUTS + layer * 1024;
    const float* wov = Wc + OFF_OUTV + layer * 1024;
    const float* wss = Wc + OFF_SCS + (layer * Z_ + z) * 1024;
    const float* wsv = Wc + OFF_SCV + (layer * Z_ + z) * 1024;
    float s2 = 0.f, v20 = 0.f, v21 = 0.f, v22 = 0.f;
    float scs = 0.f, scv0 = 0.f, scv1 = 0.f, scv2 = 0.f;
    #pragma unroll 8
    for (int c = 0; c < 32; c++) {
        float wo = wos[c * 32 + d], wv = wov[c * 32 + d];
        float wa = wss[c * 32 + d], wb = wsv[c * 32 + d];
        s2  += A_s[nl][c] * wo;
        v20 += A_v[nl][c * 3 + 0] * wv;
        v21 += A_v[nl][c * 3 + 1] * wv;
        v22 += A_v[nl][c * 3 + 2] * wv;
        scs  += B_s[nl][c] * wa;
        scv0 += B_v[nl][c * 3 + 0] * wb;
        scv1 += B_v[nl][c * 3 + 1] * wb;
        scv2 += B_v[nl][c * 3 + 2] * wb;
    }
    const float* wp = Wc + OFF_WP + (layer * Z_ + z) * 160;
    float we0 = wp[d], we1 = wp[32 + d], we2 = wp[64 + d], we3 = wp[96 + d], we4 = wp[128 + d];
    float ps = we0 * s2 + we1 * s2 * s2 + we2 * (v20 * v20 + v21 * v21 + v22 * v22);
    float pv0 = we3 * v20 + we4 * s2 * v20;
    float pv1 = we3 * v21 + we4 * s2 * v21;
    float pv2 = we3 * v22 + we4 * s2 * v22;
    __syncthreads();
    A_s[nl][d] = ps;
    A_v[nl][d * 3 + 0] = pv0;
    A_v[nl][d * 3 + 1] = pv1;
    A_v[nl][d * 3 + 2] = pv2;
    __syncthreads();
    const float* wls = Wc + OFF_LINS + layer * 1024;
    const float* wlv = Wc + OFF_LINV + layer * 1024;
    float sn = scs, vn0 = scv0, vn1 = scv1, vn2 = scv2;
    #pragma unroll 8
    for (int c = 0; c < 32; c++) {
        float wl = wls[c * 32 + d], w2_ = wlv[c * 32 + d];
        sn  += A_s[nl][c] * wl;
        vn0 += A_v[nl][c * 3 + 0] * w2_;
        vn1 += A_v[nl][c * 3 + 1] * w2_;
        vn2 += A_v[nl][c * 3 + 2] * w2_;
    }
    s[n * 32 + d] = sn;
    out[(size_t)n * 64 + layer * 32 + d] = sn;   // fp32 output (verified round 5)
    vbst[n * 96 + d * 3 + 0] = __float2bfloat16(vn0);
    vbst[n * 96 + d * 3 + 1] = __float2bfloat16(vn1);
    vbst[n * 96 + d * 3 + 2] = __float2bfloat16(vn2);

    if (fuse) {
        __syncthreads();
        B_s[nl][d]         = sn;
        B_v[nl][d * 3 + 0] = vn0;
        B_v[nl][d * 3 + 1] = vn1;
        B_v[nl][d * 3 + 2] = vn2;
        __syncthreads();
        const float* wus = Wc + OFF_UPS + (layer + 1) * 1024;
        const float* wuv = Wc + OFF_UPV + (layer + 1) * 1024;
        float a0 = 0.f, b0 = 0.f, b1 = 0.f, b2 = 0.f;
        #pragma unroll 8
        for (int c = 0; c < 32; c++) {
            float wS = wus[c * 32 + d], wV = wuv[c * 32 + d];
            a0 += B_s[nl][c] * wS;
            b0 += B_v[nl][c * 3 + 0] * wV;
            b1 += B_v[nl][c * 3 + 1] * wV;
            b2 += B_v[nl][c * 3 + 2] * wV;
        }
        su[n * 32 + d] = __float2bfloat16(a0);
        vu[n * 96 + d * 3 + 0] = __float2bfloat16(b0);
        vu[n * 96 + d * 3 + 1] = __float2bfloat16(b1);
        vu[n * 96 + d * 3 + 2] = __float2bfloat16(b2);
    }
}

// Host-side: resolve input pointers by element count (robust to harness input
// ordering). Greedy first-unused match preserves relative order within equal
// sizes, so if the harness order == reference dict order this is the identity.
static void resolve_inputs(const int* in_sizes, int n_in, int idx[17]) {
    const int want[17] = {150000, 500000, 2400000, 320, 2048, 2048, 1024, 8192,
                          20480, 2048, 2048, 20480, 20480, 3200, 2048, 2048, 1600000};
    for (int k = 0; k < 17; k++) idx[k] = k;   // default identity
    if (!in_sizes || n_in < 17) return;
    bool used[64];
    for (int i = 0; i < 64; i++) used[i] = false;
    int tmp[17];
    for (int k = 0; k < 17; k++) {
        int found = -1;
        for (int i = 0; i < n_in && i < 64; i++) {
            if (!used[i] && in_sizes[i] == want[k]) { found = i; break; }
        }
        if (found < 0) return;               // sizes don't match expectation: keep identity
        used[found] = true;
        tmp[k] = found;
    }
    for (int k = 0; k < 17; k++) idx[k] = tmp[k];
}

extern "C" void kernel_launch(void* const* d_in, const int* in_sizes, int n_in,
                              void* d_out, int out_size, void* d_ws, size_t ws_size,
                              hipStream_t stream) {
    (void)out_size; (void)ws_size;
    int idx[17];
    resolve_inputs(in_sizes, n_in, idx);

    const void* pos    = d_in[idx[0]];
    const void* attrs  = d_in[idx[1]];
    const void* shifts = d_in[idx[2]];
    const int*  ei     = (const int*)d_in[idx[16]];
    float* out = (float*)d_out;

    int*   I = (int*)d_ws;
    float* W = (float*)d_ws;

    hipMemsetAsync(I, 0, 64 * sizeof(int), stream);                             // cnt + flags
    hipMemsetAsync(I + O_ROWP, 0, 50048 * sizeof(int), stream);                 // degrees
    hipMemsetAsync(W + O_VB, 0, (size_t)N_ * C_ * 3 * sizeof(bf16), stream);    // v state = 0

    detect_kernel<<<1, 256, 0, stream>>>((const unsigned*)attrs, I + O_FLAG);
    shiftchk_kernel<<<2048, 256, 0, stream>>>((const unsigned*)shifts, I + O_FLAG, I + O_SHZ);

    ConvArgs ca;
    for (int k = 0; k < 13; k++) ca.p[k] = d_in[idx[3 + k]];
    convert_kernel<<<(W_TOTAL + 255) / 256, 256, 0, stream>>>(ca, I + O_FLAG, W + O_W);
    posconv_kernel<<<(N_ * 3 + 255) / 256, 256, 0, stream>>>(pos, I + O_FLAG, W + O_POSF);
    spec_kernel<<<(N_ + 255) / 256, 256, 0, stream>>>(attrs, I + O_FLAG, I + O_SPEC);
    embup_kernel<<<1, 320, 0, stream>>>(W + O_W, W + O_EMBU);
    sinit_kernel<<<(N_ * C_) / 256, 256, 0, stream>>>(W + O_W, W + O_EMBU, I + O_SPEC,
                                                      W + O_S, (bf16*)(W + O_SUB),
                                                      (bf16*)(W + O_VUB));

    // radial w-table (both layers; needs converted weights)
    tab_kernel<<<2 * NT_, 256, 0, stream>>>(W + O_W, W + O_TAB);

    // one-time dst-sorted active-edge list (counting sort; graph static across layers)
    deg_kernel<<<E_ / 256, 256, 0, stream>>>(ei, W + O_POSF, shifts, I + O_FLAG, I + O_ROWP);
    scan_kernel<<<1, 1024, 0, stream>>>(I + O_ROWP, I + O_CNT);
    scatter_kernel<<<E_ / 256, 256, 0, stream>>>(ei, W + O_POSF, shifts, I + O_FLAG,
                                                 I + O_ROWP, (unsigned*)(I + O_SD),
                                                 I + O_EID2);

    for (int l = 0; l < 2; l++) {
        hipMemsetAsync(W + O_SS, 0, (size_t)N_ * C_ * 4 * sizeof(float), stream);  // SS+VV
        msg_kernel<<<(E_ + 63) / 64, 256, 0, stream>>>((const unsigned*)(I + O_SD),
                                                       I + O_EID2, I + O_CNT,
                                                       W + O_POSF, shifts, I,
                                                       W + O_TAB,
                                                       (const bf16*)(W + O_SUB),
                                                       (const bf16*)(W + O_VUB),
                                                       W + O_SS, W + O_VV, l);
        post_kernel<<<N_ / 8, 256, 0, stream>>>(W + O_W, W + O_SS, W + O_VV,
                                                W + O_S, (bf16*)(W + O_VB),
                                                I + O_SPEC, out,
                                                (bf16*)(W + O_SUB), (bf16*)(W + O_VUB),
                                                (l == 0) ? 1 : 0, l);
    }
}

// Round 11
// 481.656 us; speedup vs baseline: 1.5326x; 1.1744x over previous
//
#include <hip/hip_runtime.h>
#include <hip/hip_bf16.h>

typedef __hip_bfloat16 bf16;

// Problem constants
constexpr int N_ = 50000;
constexpr int E_ = 800000;
constexpr int C_ = 32;
constexpr int Z_ = 10;

// fp32 weight arena offsets (floats)
constexpr int OFF_EMB  = 0;                    // [Z][C]          320
constexpr int OFF_UPS  = 320;                  // [L][C][C]       2048
constexpr int OFF_UPV  = OFF_UPS + 2048;       // [L][C][C]       2048
constexpr int OFF_R1T  = OFF_UPV + 2048;       // [L][64][8]  (transposed)  1024
constexpr int OFF_R2   = OFF_R1T + 1024;       // [L][64][64]     8192
constexpr int OFF_R3T  = OFF_R2 + 8192;        // [L][32][5][64] (c-major) 20480
constexpr int OFF_OUTS = OFF_R3T + 20480;      // [L][C][C]       2048
constexpr int OFF_OUTV = OFF_OUTS + 2048;      // [L][C][C]       2048
constexpr int OFF_SCS  = OFF_OUTV + 2048;      // [L][Z][C][C]    20480
constexpr int OFF_SCV  = OFF_SCS + 20480;      // [L][Z][C][C]    20480
constexpr int OFF_WP   = OFF_SCV + 20480;      // [L][Z][5][C]    3200
constexpr int OFF_LINS = OFF_WP + 3200;        // [L][C][C]       2048
constexpr int OFF_LINV = OFF_LINS + 2048;      // [L][C][C]       2048
constexpr int W_TOTAL  = OFF_LINV + 2048;      // 86464

// workspace layout, in 4-byte words (within proven 56.41 MiB arena)
constexpr size_t O_CNT  = 0;                   // int: active edge count
constexpr size_t O_FLAG = 1;                   // int: 1 => float inputs are bf16
constexpr size_t O_SHZ  = 2;                   // int: 1 => shifts are NONZERO
constexpr size_t O_BSUM = 8;                   // 49 ints: scan block sums (in zeroed 64)
constexpr size_t O_SPEC = 64;                  // N ints (padded 50048)
constexpr size_t O_SD   = 50112;               // 250000 u32: (src<<16)|dst, dst-sorted
constexpr size_t O_EID2 = 300112;              // 250000 int: original edge id per slot
                                               //   (consumed only when shifts nonzero)
constexpr size_t O_TAB  = 550112;              // [L=2][512][32][8] fp32 w-table, 262144
constexpr size_t O_EMBU = 812256;              // [Z][C] fp32 embup = emb@Wus0, 320 words
constexpr size_t O_POSF = 850112;              // N*3 fp32 (padded 150016)
constexpr size_t O_W    = 1000128;             // W_TOTAL fp32
constexpr size_t O_S    = 1086592;             // N*C fp32 (state s)
constexpr size_t O_VB   = 2686592;             // N*C*3 bf16 (state v, 2400000 words)
constexpr size_t O_SUB  = 5086592;             // N*C bf16   (800000 words)
constexpr size_t O_VUB  = 5886592;             // N*C*3 bf16 (2400000 words)
constexpr size_t O_SS   = 8286592;             // N*C fp32   (S accum)
constexpr size_t O_VV   = 9886592;             // N*C*3 fp32 (V accum) -> ends 14686592
constexpr size_t O_ROWP = 14686592;            // N ints (padded 50048): rowptr (destructive)

constexpr int NT_ = 512;                       // radial table points over r in [0,5]
constexpr int SCB_ = 1024;                     // scan: elements per block
constexpr int NSB_ = (N_ + SCB_ - 1) / SCB_;   // 49 scan blocks (<= 64 for scanB wave)

struct ConvArgs { const void* p[13]; };

// dual-dtype input load: isb is wave-uniform => scalar branch
__device__ __forceinline__ float ldi(const void* p, int i, int isb) {
    if (isb) return (float)((const bf16*)p)[i];
    return ((const float*)p)[i];
}
__device__ __forceinline__ float b2f(unsigned short u) {   // bf16 bits -> float
    union { unsigned x; float f; } v; v.x = ((unsigned)u) << 16; return v.f;
}

// ---- dtype detection on node_attrs (one-hot): word 0x00003F80 occurs only if bf16 ----
__global__ __launch_bounds__(256) void detect_kernel(const unsigned* __restrict__ a,
                                                     int* __restrict__ flag) {
    int t = threadIdx.x;
    int hit = 0;
    for (int i = t; i < 4096; i += 256) hit |= (a[i] == 0x00003F80u) ? 1 : 0;
    if (hit) atomicOr(flag, 1);
}

// ---- shifts nonzero detection (any nonzero word -> shz=1). Runs after detect. ----
__global__ __launch_bounds__(256) void shiftchk_kernel(const unsigned* __restrict__ sh,
                                                       const int* __restrict__ flag,
                                                       int* __restrict__ shz) {
    int words = (*flag) ? (E_ * 3 / 2) : (E_ * 3);
    int t = blockIdx.x * 256 + threadIdx.x;
    int hit = 0;
    for (int i = t; i < words; i += 2048 * 256) hit |= (sh[i] != 0u) ? 1 : 0;
    if (hit) atomicOr(shz, 1);
}

// ---- weight conversion (-> fp32, with R1/R3 transposes) ----
__global__ __launch_bounds__(256) void convert_kernel(ConvArgs a, const int* __restrict__ flag,
                                                      float* __restrict__ Wc) {
    int t = blockIdx.x * 256 + threadIdx.x;
    if (t >= W_TOTAL) return;
    int isb = *flag;
    int u = t;
    if (u < 320)  { Wc[OFF_EMB + u] = ldi(a.p[0], u, isb); return; }  u -= 320;
    if (u < 2048) { Wc[OFF_UPS + u] = ldi(a.p[1], u, isb); return; }  u -= 2048;
    if (u < 2048) { Wc[OFF_UPV + u] = ldi(a.p[2], u, isb); return; }  u -= 2048;
    if (u < 1024) {                       // R1 [L][8][64] -> R1T [L][64][8]
        int l = u >> 9, r = u & 511, j = r >> 3, k = r & 7;
        Wc[OFF_R1T + u] = ldi(a.p[3], l * 512 + k * 64 + j, isb); return;
    }  u -= 1024;
    if (u < 8192) { Wc[OFF_R2 + u] = ldi(a.p[4], u, isb); return; }   u -= 8192;
    if (u < 20480) {                      // R3 [L][64][160] -> R3T [L][32][5][64] (c-major)
        int l = u / 10240, r = u % 10240, c = r / 320, r2 = r % 320, p = r2 / 64, j = r2 % 64;
        Wc[OFF_R3T + u] = ldi(a.p[5], l * 10240 + j * 160 + p * 32 + c, isb); return;
    }  u -= 20480;
    if (u < 2048)  { Wc[OFF_OUTS + u] = ldi(a.p[6], u, isb);  return; } u -= 2048;
    if (u < 2048)  { Wc[OFF_OUTV + u] = ldi(a.p[7], u, isb);  return; } u -= 2048;
    if (u < 20480) { Wc[OFF_SCS  + u] = ldi(a.p[8], u, isb);  return; } u -= 20480;
    if (u < 20480) { Wc[OFF_SCV  + u] = ldi(a.p[9], u, isb);  return; } u -= 20480;
    if (u < 3200)  { Wc[OFF_WP   + u] = ldi(a.p[10], u, isb); return; } u -= 3200;
    if (u < 2048)  { Wc[OFF_LINS + u] = ldi(a.p[11], u, isb); return; } u -= 2048;
    Wc[OFF_LINV + u] = ldi(a.p[12], u, isb);
}

// ---- positions -> fp32 ----
__global__ __launch_bounds__(256) void posconv_kernel(const void* __restrict__ pos,
                                                      const int* __restrict__ flag,
                                                      float* __restrict__ posf) {
    int t = blockIdx.x * 256 + threadIdx.x;
    if (t >= N_ * 3) return;
    posf[t] = ldi(pos, t, *flag);
}

// ---- species from one-hot ----
__global__ __launch_bounds__(256) void spec_kernel(const void* __restrict__ attrs,
                                                   const int* __restrict__ flag,
                                                   int* __restrict__ spec) {
    int n = blockIdx.x * 256 + threadIdx.x;
    if (n >= N_) return;
    int isb = *flag;
    int z = 0;
    #pragma unroll
    for (int zz = 0; zz < Z_; zz++)
        if (ldi(attrs, n * Z_ + zz, isb) > 0.5f) z = zz;
    spec[n] = z;
}

// ---- embup[z][d] = sum_c emb[z][c] * Wus0[c][d]  (replaces up_kernel for l=0) ----
__global__ __launch_bounds__(320) void embup_kernel(const float* __restrict__ Wc,
                                                    float* __restrict__ embup) {
    int t = threadIdx.x;
    if (t >= 320) return;
    int z = t >> 5, d = t & 31;
    float a = 0.f;
    #pragma unroll 8
    for (int c = 0; c < 32; c++)
        a += Wc[OFF_EMB + z * 32 + c] * Wc[OFF_UPS + c * 32 + d];
    embup[t] = a;
}

// ---- s init: s = emb[spec]; su = bf16(embup[spec]); vu = 0 (v=0 at l=0) ----
__global__ __launch_bounds__(256) void sinit_kernel(const float* __restrict__ Wc,
                                                    const float* __restrict__ embup,
                                                    const int* __restrict__ spec,
                                                    float* __restrict__ s,
                                                    bf16* __restrict__ su,
                                                    bf16* __restrict__ vu) {
    int t = blockIdx.x * 256 + threadIdx.x;   // N*C threads
    int n = t >> 5, c = t & 31;
    int z = spec[n];
    s[t] = Wc[OFF_EMB + z * C_ + c];
    su[t] = __float2bfloat16(embup[z * C_ + c]);
    vu[t * 3 + 0] = __float2bfloat16(0.f);
    vu[t * 3 + 1] = __float2bfloat16(0.f);
    vu[t * 3 + 2] = __float2bfloat16(0.f);
}

__device__ __forceinline__ float silu_f(float a) {
    return a / (1.f + __expf(-a));
}

// ---- radial w-table build: tab[l][k][c][8] = (h2(r_k) @ R3T)[c][p], p in 0..4 ----
__global__ __launch_bounds__(256) void tab_kernel(const float* __restrict__ Wc,
                                                  float* __restrict__ tab) {
    __shared__ float h1s[64];
    __shared__ float h2s[64];
    int bk = blockIdx.x;               // 0..1023 = l*512 + k
    int l = bk >> 9, k = bk & 511;
    int t = threadIdx.x;
    float r = (5.0f / (float)(NT_ - 1)) * (float)k;
    float rs = fmaxf(r, 1e-9f);
    float inv = 1.0f / rs;
    float x = r * 0.2f;
    float x2 = x * x, x3 = x2 * x, x6 = x3 * x3, x7 = x6 * x, x8 = x7 * x;
    float fcv = 1.f - 28.f * x6 + 48.f * x7 - 21.f * x8;
    float scl = 0.63245553203367587f * inv * fcv;
    float ef[8];
    #pragma unroll
    for (int q = 0; q < 8; q++)
        ef[q] = scl * sinf(0.62831853071795865f * rs * (float)(q + 1));

    const float* r1  = Wc + OFF_R1T + l * 512;    // [64][8]
    const float* r2w = Wc + OFF_R2  + l * 4096;   // [64][64]
    const float* r3l = Wc + OFF_R3T + l * 10240;  // [32][5][64]
    if (t < 64) {
        float a = 0.f;
        #pragma unroll
        for (int q = 0; q < 8; q++) a += ef[q] * r1[t * 8 + q];
        h1s[t] = silu_f(a);
    }
    __syncthreads();
    if (t < 64) {
        float a = 0.f;
        for (int kk = 0; kk < 64; kk++) a += h1s[kk] * r2w[kk * 64 + t];
        h2s[t] = silu_f(a);
    }
    __syncthreads();
    if (t < 160) {
        int c = t / 5, p = t % 5;
        const float* rp = r3l + (c * 5 + p) * 64;
        float a = 0.f;
        for (int j = 0; j < 64; j++) a += h2s[j] * rp[j];
        tab[(((size_t)l * NT_ + k) * 32 + c) * 8 + p] = a;
    }
}

// ---- dst-sort build step 1: per-dst degree of ACTIVE edges (r < RCUT) ----
__global__ __launch_bounds__(256) void deg_kernel(const int* __restrict__ ei,
                                                  const float* __restrict__ posf,
                                                  const void* __restrict__ shifts,
                                                  const int* __restrict__ flag,
                                                  int* __restrict__ rp) {
    int e = blockIdx.x * 256 + threadIdx.x;
    int isb = *flag;
    int s = ei[e], d = ei[E_ + e];
    if (s < 0 || s >= N_ || d < 0 || d >= N_) return;
    float vx = posf[d * 3 + 0] - posf[s * 3 + 0] + ldi(shifts, e * 3 + 0, isb);
    float vy = posf[d * 3 + 1] - posf[s * 3 + 1] + ldi(shifts, e * 3 + 1, isb);
    float vz = posf[d * 3 + 2] - posf[s * 3 + 2] + ldi(shifts, e * 3 + 2, isb);
    if (vx * vx + vy * vy + vz * vz < 25.0f) atomicAdd(rp + d, 1);
}

// ---- step 2 (round-11): MULTI-BLOCK exclusive scan, replaces the single-block
// scan_kernel that was the LARGEST dispatch in the pipeline (93us at 0.16%
// occupancy: one block streaming 400KB through one CU's load queue).
// scanA: per-block sums -> bsum[49]; scanB: 1-wave shfl scan of bsum + cnt;
// scanC: in-block exclusive scan + block offset, in place. ~3us each. ----
__global__ __launch_bounds__(256) void scanA_kernel(const int* __restrict__ rp,
                                                    int* __restrict__ bsum) {
    __shared__ int red[256];
    int b = blockIdx.x, t = threadIdx.x;
    int base = b * SCB_ + t * 4;
    int s = 0;
    #pragma unroll
    for (int i = 0; i < 4; i++) { int idx = base + i; if (idx < N_) s += rp[idx]; }
    red[t] = s;
    __syncthreads();
    for (int off = 128; off > 0; off >>= 1) {
        if (t < off) red[t] += red[t + off];
        __syncthreads();
    }
    if (t == 0) bsum[b] = red[0];
}

__global__ __launch_bounds__(64) void scanB_kernel(int* __restrict__ bsum,
                                                   int* __restrict__ cnt) {
    int t = threadIdx.x;                      // single wave64
    int v = (t < NSB_) ? bsum[t] : 0;
    int inc = v;
    #pragma unroll
    for (int off = 1; off < 64; off <<= 1) {
        int u = __shfl_up(inc, off, 64);
        if (t >= off) inc += u;
    }
    if (t < NSB_) bsum[t] = inc - v;          // exclusive block offsets
    if (t == 63) cnt[0] = inc;                // grand total (lanes >= NSB_ add 0)
}

__global__ __launch_bounds__(256) void scanC_kernel(int* __restrict__ rp,
                                                    const int* __restrict__ bsum) {
    __shared__ int ps[256];
    int b = blockIdx.x, t = threadIdx.x;
    int base = b * SCB_ + t * 4;
    int v0 = 0, v1 = 0, v2 = 0, v3 = 0;
    if (base + 0 < N_) v0 = rp[base + 0];
    if (base + 1 < N_) v1 = rp[base + 1];
    if (base + 2 < N_) v2 = rp[base + 2];
    if (base + 3 < N_) v3 = rp[base + 3];
    int s = v0 + v1 + v2 + v3;
    ps[t] = s;
    __syncthreads();
    for (int off = 1; off < 256; off <<= 1) {
        int u = (t >= off) ? ps[t - off] : 0;
        __syncthreads();
        ps[t] += u;
        __syncthreads();
    }
    int run = bsum[b] + ((t == 0) ? 0 : ps[t - 1]);
    if (base + 0 < N_) { rp[base + 0] = run; run += v0; }
    if (base + 1 < N_) { rp[base + 1] = run; run += v1; }
    if (base + 2 < N_) { rp[base + 2] = run; run += v2; }
    if (base + 3 < N_) { rp[base + 3] = run; run += v3; }
}

// ---- step 3: counting-sort scatter; writes packed (src<<16|dst) + edge id ----
__global__ __launch_bounds__(256) void scatter_kernel(const int* __restrict__ ei,
                                                      const float* __restrict__ posf,
                                                      const void* __restrict__ shifts,
                                                      const int* __restrict__ flag,
                                                      int* __restrict__ rp,
                                                      unsigned* __restrict__ sdArr,
                                                      int* __restrict__ eidArr) {
    int e = blockIdx.x * 256 + threadIdx.x;
    int isb = *flag;
    int s = ei[e], d = ei[E_ + e];
    if (s < 0 || s >= N_ || d < 0 || d >= N_) return;
    float vx = posf[d * 3 + 0] - posf[s * 3 + 0] + ldi(shifts, e * 3 + 0, isb);
    float vy = posf[d * 3 + 1] - posf[s * 3 + 1] + ldi(shifts, e * 3 + 1, isb);
    float vz = posf[d * 3 + 2] - posf[s * 3 + 2] + ldi(shifts, e * 3 + 2, isb);
    if (vx * vx + vy * vy + vz * vz < 25.0f) {
        int pos = atomicAdd(rp + d, 1);
        sdArr[pos] = ((unsigned)s << 16) | (unsigned)d;   // N=50000 < 2^16
        eidArr[pos] = e;
    }
}

// segmented inclusive sum over the 16 groups of a wave (stride-4 lanes).
__device__ __forceinline__ float segsum16(float v, int lane, int g, int hdv) {
    #pragma unroll
    for (int s = 1; s < 16; s <<= 1) {
        float u = __shfl(v, (lane - 4 * s) & 63, 64);
        if (g - s >= hdv) v += u;
    }
    return v;
}

// ---- fused edge kernel, 4 lanes per edge, dst-sorted slots (r10-proven) ----
__global__ __launch_bounds__(256, 4) void msg_kernel(const unsigned* __restrict__ sd,
                                                     const int* __restrict__ eidA,
                                                     const int* __restrict__ cnt,
                                                     const float* __restrict__ posf,
                                                     const void* __restrict__ shifts,
                                                     const int* __restrict__ flags,
                                                     const float* __restrict__ tab,
                                                     const bf16* __restrict__ sub,
                                                     const bf16* __restrict__ vub,
                                                     float* __restrict__ S,
                                                     float* __restrict__ V, int layer) {
    // XCD swizzle: within each 128-block super-tile, XCD k (= bid%8) gets a
    // CONTIGUOUS run of G=16 edge tiles. Bijective (8xG transpose); identity
    // on the tail below one super-tile.
    constexpr int G = 16, SUP = 8 * G;
    int bid = blockIdx.x;
    int nfull = ((int)gridDim.x / SUP) * SUP;
    int sbid = bid;
    if (bid < nfull) {
        int sup = bid / SUP, rr = bid % SUP;
        sbid = sup * SUP + (rr % 8) * G + (rr / 8);
    }

    int tid = threadIdx.x;
    int lane = tid & 63;
    int waveid = tid >> 6;
    int g = lane >> 2;                 // group within wave (0..15)
    int l = lane & 3;                  // lane within group (0..3)
    int total = cnt[0];
    int base = sbid * 64 + waveid * 16;
    if (base >= total) return;         // wave-uniform early out
    int i0 = base + g;
    bool valid = (i0 < total);
    int i = valid ? i0 : (total - 1);  // clamp tail; contribution zeroed via scale
    unsigned sdv = sd[i];
    int srcn = (int)(sdv >> 16), dstn = (int)(sdv & 0xFFFFu);
    float scale = valid ? 0.0625f : 0.0f;

    // ---- exact run topology (global, via sequential peeks) ----
    bool head_ex = valid && (i == 0 || (int)(sd[i - 1] & 0xFFFFu) != dstn);
    bool last_ex = valid && (i == total - 1 || (int)(sd[i + 1] & 0xFFFFu) != dstn);
    int dstx = __shfl(dstn, (lane + 4) & 63, 64);
    bool last_wt = (g == 15) || (dstx != dstn);     // within-tile run end (writer)
    int hv = head_ex ? g + 1 : 0;                   // max-scan of exact head pos+1
    #pragma unroll
    for (int s2 = 1; s2 < 16; s2 <<= 1) {
        int o = __shfl(hv, (lane - 4 * s2) & 63, 64);
        if (g >= s2) hv = max(hv, o);
    }
    int hdv = (hv > 0) ? hv - 1 : 0;
    bool complete = last_ex && (hv > 0);            // run fully inside this tile

    // strided channel base pointers (lane owns c = 4*c4 + l)
    const unsigned short* sp = (const unsigned short*)(sub + (size_t)srcn * 32 + l);
    const unsigned short* vp = (const unsigned short*)(vub + (size_t)srcn * 96 + 3 * l);
    unsigned short pf_s  = sp[0];
    unsigned short pf_v0 = vp[0], pf_v1 = vp[1], pf_v2 = vp[2];

    float vx = posf[dstn * 3 + 0] - posf[srcn * 3 + 0];
    float vy = posf[dstn * 3 + 1] - posf[srcn * 3 + 1];
    float vz = posf[dstn * 3 + 2] - posf[srcn * 3 + 2];
    if (flags[O_SHZ]) {                // shifts nonzero: rare fallback path
        int isb = flags[O_FLAG];
        int e = eidA[i];
        vx += ldi(shifts, e * 3 + 0, isb);
        vy += ldi(shifts, e * 3 + 1, isb);
        vz += ldi(shifts, e * 3 + 2, isb);
    }
    float r2 = vx * vx + vy * vy + vz * vz;
    float r = sqrtf(r2);
    float rs = fmaxf(r, 1e-9f);
    float inv = 1.0f / rs;
    float Yx = vx * inv, Yy = vy * inv, Yz = vz * inv;

    // table coordinates: r in [0,5) -> k0 in [0,510], frac f
    float tpos = r * ((float)(NT_ - 1) / 5.0f);
    int k0 = min((int)tpos, NT_ - 2);
    float f = tpos - (float)k0;
    const float* t0 = tab + ((size_t)layer * NT_ + k0) * 256;   // 32 ch * 8 floats
    const float* t1 = t0 + 256;

    // prefetch chunk 0's table rows (channel c = l)
    float4 pf_wa = *(const float4*)(t0 + l * 8);
    float  pf_wa4 = (t0 + l * 8)[4];
    float4 pf_wb = *(const float4*)(t1 + l * 8);
    float  pf_wb4 = (t1 + l * 8)[4];

    float* Sd = S + (size_t)dstn * 32;
    float* Vd = V + (size_t)dstn * 96;

    // RUNTIME c4 loop; named-scalar rolling prefetch, no dynamic register
    // indexing anywhere. c4=7 prefetch reads past the row (still inside the
    // allocated workspace arena) and is never consumed.
    #pragma unroll 1
    for (int c4 = 0; c4 < 8; c4++) {
        float ss  = b2f(pf_s);
        float vvx = b2f(pf_v0);
        float vvy = b2f(pf_v1);
        float vvz = b2f(pf_v2);
        float4 wa = pf_wa; float wa4 = pf_wa4;
        float4 wb = pf_wb; float wb4 = pf_wb4;

        // prefetch next chunk (states + table)
        pf_s  = sp[4 * c4 + 4];
        pf_v0 = vp[12 * c4 + 12];
        pf_v1 = vp[12 * c4 + 13];
        pf_v2 = vp[12 * c4 + 14];
        int noff = (4 * c4 + 4 + l) * 8;
        pf_wa = *(const float4*)(t0 + noff);
        pf_wa4 = (t0 + noff)[4];
        pf_wb = *(const float4*)(t1 + noff);
        pf_wb4 = (t1 + noff)[4];

        // lerp the 5 path weights for this lane's channel c = 4*c4 + l
        float w0 = wa.x + f * (wb.x - wa.x);
        float w1 = wa.y + f * (wb.y - wa.y);
        float w2 = wa.z + f * (wb.z - wa.z);
        float w3 = wa.w + f * (wb.w - wa.w);
        float w4 = wa4 + f * (wb4 - wa4);

        const int c = 4 * c4 + l;
        float dt = vvx * Yx + vvy * Yy + vvz * Yz;
        float cx = vvy * Yz - vvz * Yy;
        float cy = vvz * Yx - vvx * Yz;
        float cz = vvx * Yy - vvy * Yx;
        float ms = (w0 * ss + w3 * dt) * scale;
        float mx = (w1 * ss * Yx + w2 * vvx + w4 * cx) * scale;
        float my = (w1 * ss * Yy + w2 * vvy + w4 * cy) * scale;
        float mz = (w1 * ss * Yz + w2 * vvz + w4 * cz) * scale;

        // pre-sum each same-dst run; only the within-tile run-last group writes
        ms = segsum16(ms, lane, g, hdv);
        mx = segsum16(mx, lane, g, hdv);
        my = segsum16(my, lane, g, hdv);
        mz = segsum16(mz, lane, g, hdv);
        if (last_wt) {
            if (complete) {            // run fully in-tile: plain stores
                Sd[c] = ms;
                Vd[c * 3 + 0] = mx;
                Vd[c * 3 + 1] = my;
                Vd[c * 3 + 2] = mz;
            } else {                   // split across tiles: atomic partials
                atomicAdd(Sd + c, ms);
                atomicAdd(Vd + c * 3 + 0, mx);
                atomicAdd(Vd + c * 3 + 1, my);
                atomicAdd(Vd + c * 3 + 2, mz);
            }
        }
    }
}

// ---- per-node post: out/skip/product/linear, writes invariants + new s,v in-place.
// When fuse!=0 also computes next layer's "up" (su/vu) from the fresh s,v. ----
__global__ __launch_bounds__(256) void post_kernel(const float* __restrict__ Wc,
                                                   const float* __restrict__ Sb,
                                                   const float* __restrict__ Vb,
                                                   float* __restrict__ s,
                                                   bf16* __restrict__ vbst,
                                                   const int* __restrict__ spec,
                                                   float* __restrict__ out,
                                                   bf16* __restrict__ su,
                                                   bf16* __restrict__ vu,
                                                   int fuse, int layer) {
    __shared__ float A_s[8][32];
    __shared__ float A_v[8][96];
    __shared__ float B_s[8][32];
    __shared__ float B_v[8][96];
    int tid = threadIdx.x;
    int nl = tid >> 5, d = tid & 31;
    int n = blockIdx.x * 8 + nl;
    A_s[nl][d]      = Sb[n * 32 + d];
    A_v[nl][d]      = Vb[n * 96 + d];
    A_v[nl][d + 32] = Vb[n * 96 + d + 32];
    A_v[nl][d + 64] = Vb[n * 96 + d + 64];
    B_s[nl][d]      = s[n * 32 + d];
    B_v[nl][d]      = (float)vbst[n * 96 + d];
    B_v[nl][d + 32] = (float)vbst[n * 96 + d + 32];
    B_v[nl][d + 64] = (float)vbst[n * 96 + d + 64];
    __syncthreads();

    int z = spec[n];
    const float* wos = Wc + OFF_OUTS + layer * 1024;
    const float* wov = Wc + OFF_OUTV + layer * 1024;
    const float* wss = Wc + OFF_SCS + (layer * Z_ + z) * 1024;
    const float* wsv = Wc + OFF_SCV + (layer * Z_ + z) * 1024;
    float s2 = 0.f, v20 = 0.f, v21 = 0.f, v22 = 0.f;
    float scs = 0.f, scv0 = 0.f, scv1 = 0.f, scv2 = 0.f;
    #pragma unroll 8
    for (int c = 0; c < 32; c++) {
        float wo = wos[c * 32 + d], wv = wov[c * 32 + d];
        float wa = wss[c * 32 + d], wb = wsv[c * 32 + d];
        s2  += A_s[nl][c] * wo;
        v20 += A_v[nl][c * 3 + 0] * wv;
        v21 += A_v[nl][c * 3 + 1] * wv;
        v22 += A_v[nl][c * 3 + 2] * wv;
        scs  += B_s[nl][c] * wa;
        scv0 += B_v[nl][c * 3 + 0] * wb;
        scv1 += B_v[nl][c * 3 + 1] * wb;
        scv2 += B_v[nl][c * 3 + 2] * wb;
    }
    const float* wp = Wc + OFF_WP + (layer * Z_ + z) * 160;
    float we0 = wp[d], we1 = wp[32 + d], we2 = wp[64 + d], we3 = wp[96 + d], we4 = wp[128 + d];
    float ps = we0 * s2 + we1 * s2 * s2 + we2 * (v20 * v20 + v21 * v21 + v22 * v22);
    float pv0 = we3 * v20 + we4 * s2 * v20;
    float pv1 = we3 * v21 + we4 * s2 * v21;
    float pv2 = we3 * v22 + we4 * s2 * v22;
    __syncthreads();
    A_s[nl][d] = ps;
    A_v[nl][d * 3 + 0] = pv0;
    A_v[nl][d * 3 + 1] = pv1;
    A_v[nl][d * 3 + 2] = pv2;
    __syncthreads();
    const float* wls = Wc + OFF_LINS + layer * 1024;
    const float* wlv = Wc + OFF_LINV + layer * 1024;
    float sn = scs, vn0 = scv0, vn1 = scv1, vn2 = scv2;
    #pragma unroll 8
    for (int c = 0; c < 32; c++) {
        float wl = wls[c * 32 + d], w2_ = wlv[c * 32 + d];
        sn  += A_s[nl][c] * wl;
        vn0 += A_v[nl][c * 3 + 0] * w2_;
        vn1 += A_v[nl][c * 3 + 1] * w2_;
        vn2 += A_v[nl][c * 3 + 2] * w2_;
    }
    s[n * 32 + d] = sn;
    out[(size_t)n * 64 + layer * 32 + d] = sn;   // fp32 output (verified round 5)
    vbst[n * 96 + d * 3 + 0] = __float2bfloat16(vn0);
    vbst[n * 96 + d * 3 + 1] = __float2bfloat16(vn1);
    vbst[n * 96 + d * 3 + 2] = __float2bfloat16(vn2);

    if (fuse) {
        __syncthreads();
        B_s[nl][d]         = sn;
        B_v[nl][d * 3 + 0] = vn0;
        B_v[nl][d * 3 + 1] = vn1;
        B_v[nl][d * 3 + 2] = vn2;
        __syncthreads();
        const float* wus = Wc + OFF_UPS + (layer + 1) * 1024;
        const float* wuv = Wc + OFF_UPV + (layer + 1) * 1024;
        float a0 = 0.f, b0 = 0.f, b1 = 0.f, b2 = 0.f;
        #pragma unroll 8
        for (int c = 0; c < 32; c++) {
            float wS = wus[c * 32 + d], wV = wuv[c * 32 + d];
            a0 += B_s[nl][c] * wS;
            b0 += B_v[nl][c * 3 + 0] * wV;
            b1 += B_v[nl][c * 3 + 1] * wV;
            b2 += B_v[nl][c * 3 + 2] * wV;
        }
        su[n * 32 + d] = __float2bfloat16(a0);
        vu[n * 96 + d * 3 + 0] = __float2bfloat16(b0);
        vu[n * 96 + d * 3 + 1] = __float2bfloat16(b1);
        vu[n * 96 + d * 3 + 2] = __float2bfloat16(b2);
    }
}

// Host-side: resolve input pointers by element count (robust to harness input
// ordering). Greedy first-unused match preserves relative order within equal
// sizes, so if the harness order == reference dict order this is the identity.
static void resolve_inputs(const int* in_sizes, int n_in, int idx[17]) {
    const int want[17] = {150000, 500000, 2400000, 320, 2048, 2048, 1024, 8192,
                          20480, 2048, 2048, 20480, 20480, 3200, 2048, 2048, 1600000};
    for (int k = 0; k < 17; k++) idx[k] = k;   // default identity
    if (!in_sizes || n_in < 17) return;
    bool used[64];
    for (int i = 0; i < 64; i++) used[i] = false;
    int tmp[17];
    for (int k = 0; k < 17; k++) {
        int found = -1;
        for (int i = 0; i < n_in && i < 64; i++) {
            if (!used[i] && in_sizes[i] == want[k]) { found = i; break; }
        }
        if (found < 0) return;               // sizes don't match expectation: keep identity
        used[found] = true;
        tmp[k] = found;
    }
    for (int k = 0; k < 17; k++) idx[k] = tmp[k];
}

extern "C" void kernel_launch(void* const* d_in, const int* in_sizes, int n_in,
                              void* d_out, int out_size, void* d_ws, size_t ws_size,
                              hipStream_t stream) {
    (void)out_size; (void)ws_size;
    int idx[17];
    resolve_inputs(in_sizes, n_in, idx);

    const void* pos    = d_in[idx[0]];
    const void* attrs  = d_in[idx[1]];
    const void* shifts = d_in[idx[2]];
    const int*  ei     = (const int*)d_in[idx[16]];
    float* out = (float*)d_out;

    int*   I = (int*)d_ws;
    float* W = (float*)d_ws;

    hipMemsetAsync(I, 0, 64 * sizeof(int), stream);                             // cnt + flags
    hipMemsetAsync(I + O_ROWP, 0, 50048 * sizeof(int), stream);                 // degrees
    hipMemsetAsync(W + O_VB, 0, (size_t)N_ * C_ * 3 * sizeof(bf16), stream);    // v state = 0

    detect_kernel<<<1, 256, 0, stream>>>((const unsigned*)attrs, I + O_FLAG);
    shiftchk_kernel<<<2048, 256, 0, stream>>>((const unsigned*)shifts, I + O_FLAG, I + O_SHZ);

    ConvArgs ca;
    for (int k = 0; k < 13; k++) ca.p[k] = d_in[idx[3 + k]];
    convert_kernel<<<(W_TOTAL + 255) / 256, 256, 0, stream>>>(ca, I + O_FLAG, W + O_W);
    posconv_kernel<<<(N_ * 3 + 255) / 256, 256, 0, stream>>>(pos, I + O_FLAG, W + O_POSF);
    spec_kernel<<<(N_ + 255) / 256, 256, 0, stream>>>(attrs, I + O_FLAG, I + O_SPEC);
    embup_kernel<<<1, 320, 0, stream>>>(W + O_W, W + O_EMBU);
    sinit_kernel<<<(N_ * C_) / 256, 256, 0, stream>>>(W + O_W, W + O_EMBU, I + O_SPEC,
                                                      W + O_S, (bf16*)(W + O_SUB),
                                                      (bf16*)(W + O_VUB));

    // radial w-table (both layers; needs converted weights)
    tab_kernel<<<2 * NT_, 256, 0, stream>>>(W + O_W, W + O_TAB);

    // one-time dst-sorted active-edge list (counting sort; graph static across layers)
    deg_kernel<<<E_ / 256, 256, 0, stream>>>(ei, W + O_POSF, shifts, I + O_FLAG, I + O_ROWP);
    scanA_kernel<<<NSB_, 256, 0, stream>>>(I + O_ROWP, I + O_BSUM);
    scanB_kernel<<<1, 64, 0, stream>>>(I + O_BSUM, I + O_CNT);
    scanC_kernel<<<NSB_, 256, 0, stream>>>(I + O_ROWP, I + O_BSUM);
    scatter_kernel<<<E_ / 256, 256, 0, stream>>>(ei, W + O_POSF, shifts, I + O_FLAG,
                                                 I + O_ROWP, (unsigned*)(I + O_SD),
                                                 I + O_EID2);

    for (int l = 0; l < 2; l++) {
        hipMemsetAsync(W + O_SS, 0, (size_t)N_ * C_ * 4 * sizeof(float), stream);  // SS+VV
        msg_kernel<<<(E_ + 63) / 64, 256, 0, stream>>>((const unsigned*)(I + O_SD),
                                                       I + O_EID2, I + O_CNT,
                                                       W + O_POSF, shifts, I,
                                                       W + O_TAB,
                                                       (const bf16*)(W + O_SUB),
                                                       (const bf16*)(W + O_VUB),
                                                       W + O_SS, W + O_VV, l);
        post_kernel<<<N_ / 8, 256, 0, stream>>>(W + O_W, W + O_SS, W + O_VV,
                                                W + O_S, (bf16*)(W + O_VB),
                                                I + O_SPEC, out,
                                                (bf16*)(W + O_SUB), (bf16*)(W + O_VUB),
                                                (l == 0) ? 1 : 0, l);
    }
}

// Round 12
// 446.133 us; speedup vs baseline: 1.6547x; 1.0796x over previous
//
#include <hip/hip_runtime.h>
#include <hip/hip_bf16.h>

typedef __hip_bfloat16 bf16;

// Problem constants
constexpr int N_ = 50000;
constexpr int E_ = 800000;
constexpr int C_ = 32;
constexpr int Z_ = 10;

// fp32 weight arena offsets (floats)
constexpr int OFF_EMB  = 0;                    // [Z][C]          320
constexpr int OFF_UPS  = 320;                  // [L][C][C]       2048
constexpr int OFF_UPV  = OFF_UPS + 2048;       // [L][C][C]       2048
constexpr int OFF_R1T  = OFF_UPV + 2048;       // [L][64][8]  (transposed)  1024
constexpr int OFF_R2   = OFF_R1T + 1024;       // [L][64][64]     8192
constexpr int OFF_R3T  = OFF_R2 + 8192;        // [L][32][5][64] (c-major) 20480
constexpr int OFF_OUTS = OFF_R3T + 20480;      // [L][C][C]       2048
constexpr int OFF_OUTV = OFF_OUTS + 2048;      // [L][C][C]       2048
constexpr int OFF_SCS  = OFF_OUTV + 2048;      // [L][Z][C][C]    20480
constexpr int OFF_SCV  = OFF_SCS + 20480;      // [L][Z][C][C]    20480
constexpr int OFF_WP   = OFF_SCV + 20480;      // [L][Z][5][C]    3200
constexpr int OFF_LINS = OFF_WP + 3200;        // [L][C][C]       2048
constexpr int OFF_LINV = OFF_LINS + 2048;      // [L][C][C]       2048
constexpr int W_TOTAL  = OFF_LINV + 2048;      // 86464

// workspace layout, in 4-byte words (within proven 56.41 MiB arena)
constexpr size_t O_CNT  = 0;                   // int: active edge count
constexpr size_t O_FLAG = 1;                   // int: 1 => float inputs are bf16
constexpr size_t O_SHZ  = 2;                   // int: 1 => shifts are NONZERO
constexpr size_t O_BSUM = 8;                   // 49 ints: scan block sums (in zeroed 64)
constexpr size_t O_SPEC = 64;                  // N ints (padded 50048)
constexpr size_t O_SD   = 50112;               // 250000 u32: (src<<16)|dst, dst-sorted
constexpr size_t O_EID2 = 300112;              // 250000 int: original edge id per slot
                                               //   (consumed only when shifts nonzero)
constexpr size_t O_TAB  = 550112;              // [L=2][512][32][8] fp32 w-table, 262144
constexpr size_t O_EMBU = 812256;              // [Z][C] fp32 embup = emb@Wus0, 320 words
constexpr size_t O_POSF = 850112;              // N*3 fp32 (padded 150016)
constexpr size_t O_W    = 1000128;             // W_TOTAL fp32
constexpr size_t O_S    = 1086592;             // N*C fp32 (state s)
constexpr size_t O_VB   = 2686592;             // N*C*3 bf16 (state v, 2400000 words)
constexpr size_t O_SUB  = 5086592;             // N*C bf16   (800000 words)
constexpr size_t O_VUB  = 5886592;             // N*C*3 bf16 (2400000 words)
constexpr size_t O_SS   = 8286592;             // N*C fp32   (S accum)
constexpr size_t O_VV   = 9886592;             // N*C*3 fp32 (V accum) -> ends 14686592
constexpr size_t O_ROWP = 14686592;            // N ints (padded 50048): rowptr (destructive)

constexpr int NT_ = 512;                       // radial table points over r in [0,5]
constexpr int SCB_ = 1024;                     // scan: elements per block
constexpr int NSB_ = (N_ + SCB_ - 1) / SCB_;   // 49 scan blocks (<= 64 for scanB wave)

struct ConvArgs { const void* p[13]; };

// dual-dtype input load: isb is wave-uniform => scalar branch
__device__ __forceinline__ float ldi(const void* p, int i, int isb) {
    if (isb) return (float)((const bf16*)p)[i];
    return ((const float*)p)[i];
}
__device__ __forceinline__ float b2f(unsigned short u) {   // bf16 bits -> float
    union { unsigned x; float f; } v; v.x = ((unsigned)u) << 16; return v.f;
}

// ---- dtype detection on node_attrs (one-hot): word 0x00003F80 occurs only if bf16 ----
__global__ __launch_bounds__(256) void detect_kernel(const unsigned* __restrict__ a,
                                                     int* __restrict__ flag) {
    int t = threadIdx.x;
    int hit = 0;
    for (int i = t; i < 4096; i += 256) hit |= (a[i] == 0x00003F80u) ? 1 : 0;
    if (hit) atomicOr(flag, 1);
}

// ---- shifts nonzero detection (any nonzero word -> shz=1). Runs after detect. ----
__global__ __launch_bounds__(256) void shiftchk_kernel(const unsigned* __restrict__ sh,
                                                       const int* __restrict__ flag,
                                                       int* __restrict__ shz) {
    int words = (*flag) ? (E_ * 3 / 2) : (E_ * 3);
    int t = blockIdx.x * 256 + threadIdx.x;
    int hit = 0;
    for (int i = t; i < words; i += 2048 * 256) hit |= (sh[i] != 0u) ? 1 : 0;
    if (hit) atomicOr(shz, 1);
}

// ---- weight conversion (-> fp32, with R1/R3 transposes) ----
__global__ __launch_bounds__(256) void convert_kernel(ConvArgs a, const int* __restrict__ flag,
                                                      float* __restrict__ Wc) {
    int t = blockIdx.x * 256 + threadIdx.x;
    if (t >= W_TOTAL) return;
    int isb = *flag;
    int u = t;
    if (u < 320)  { Wc[OFF_EMB + u] = ldi(a.p[0], u, isb); return; }  u -= 320;
    if (u < 2048) { Wc[OFF_UPS + u] = ldi(a.p[1], u, isb); return; }  u -= 2048;
    if (u < 2048) { Wc[OFF_UPV + u] = ldi(a.p[2], u, isb); return; }  u -= 2048;
    if (u < 1024) {                       // R1 [L][8][64] -> R1T [L][64][8]
        int l = u >> 9, r = u & 511, j = r >> 3, k = r & 7;
        Wc[OFF_R1T + u] = ldi(a.p[3], l * 512 + k * 64 + j, isb); return;
    }  u -= 1024;
    if (u < 8192) { Wc[OFF_R2 + u] = ldi(a.p[4], u, isb); return; }   u -= 8192;
    if (u < 20480) {                      // R3 [L][64][160] -> R3T [L][32][5][64] (c-major)
        int l = u / 10240, r = u % 10240, c = r / 320, r2 = r % 320, p = r2 / 64, j = r2 % 64;
        Wc[OFF_R3T + u] = ldi(a.p[5], l * 10240 + j * 160 + p * 32 + c, isb); return;
    }  u -= 20480;
    if (u < 2048)  { Wc[OFF_OUTS + u] = ldi(a.p[6], u, isb);  return; } u -= 2048;
    if (u < 2048)  { Wc[OFF_OUTV + u] = ldi(a.p[7], u, isb);  return; } u -= 2048;
    if (u < 20480) { Wc[OFF_SCS  + u] = ldi(a.p[8], u, isb);  return; } u -= 20480;
    if (u < 20480) { Wc[OFF_SCV  + u] = ldi(a.p[9], u, isb);  return; } u -= 20480;
    if (u < 3200)  { Wc[OFF_WP   + u] = ldi(a.p[10], u, isb); return; } u -= 3200;
    if (u < 2048)  { Wc[OFF_LINS + u] = ldi(a.p[11], u, isb); return; } u -= 2048;
    Wc[OFF_LINV + u] = ldi(a.p[12], u, isb);
}

// ---- positions -> fp32 ----
__global__ __launch_bounds__(256) void posconv_kernel(const void* __restrict__ pos,
                                                      const int* __restrict__ flag,
                                                      float* __restrict__ posf) {
    int t = blockIdx.x * 256 + threadIdx.x;
    if (t >= N_ * 3) return;
    posf[t] = ldi(pos, t, *flag);
}

// ---- species from one-hot ----
__global__ __launch_bounds__(256) void spec_kernel(const void* __restrict__ attrs,
                                                   const int* __restrict__ flag,
                                                   int* __restrict__ spec) {
    int n = blockIdx.x * 256 + threadIdx.x;
    if (n >= N_) return;
    int isb = *flag;
    int z = 0;
    #pragma unroll
    for (int zz = 0; zz < Z_; zz++)
        if (ldi(attrs, n * Z_ + zz, isb) > 0.5f) z = zz;
    spec[n] = z;
}

// ---- embup[z][d] = sum_c emb[z][c] * Wus0[c][d] (layer-0 su lookup table) ----
__global__ __launch_bounds__(320) void embup_kernel(const float* __restrict__ Wc,
                                                    float* __restrict__ embup) {
    int t = threadIdx.x;
    if (t >= 320) return;
    int z = t >> 5, d = t & 31;
    float a = 0.f;
    #pragma unroll 8
    for (int c = 0; c < 32; c++)
        a += Wc[OFF_EMB + z * 32 + c] * Wc[OFF_UPS + c * 32 + d];
    embup[t] = a;
}

// ---- s init: s = emb[spec] only. Layer-0 msg reads embup[spec] directly
// (no sub/vub needed); layer-1 su/vu are produced by fused post(l=0). ----
__global__ __launch_bounds__(256) void sinit_kernel(const float* __restrict__ Wc,
                                                    const int* __restrict__ spec,
                                                    float* __restrict__ s) {
    int t = blockIdx.x * 256 + threadIdx.x;   // N*C threads
    int n = t >> 5, c = t & 31;
    s[t] = Wc[OFF_EMB + spec[n] * C_ + c];
}

__device__ __forceinline__ float silu_f(float a) {
    return a / (1.f + __expf(-a));
}

// ---- radial w-table build: tab[l][k][c][8] = (h2(r_k) @ R3T)[c][p], p in 0..4 ----
__global__ __launch_bounds__(256) void tab_kernel(const float* __restrict__ Wc,
                                                  float* __restrict__ tab) {
    __shared__ float h1s[64];
    __shared__ float h2s[64];
    int bk = blockIdx.x;               // 0..1023 = l*512 + k
    int l = bk >> 9, k = bk & 511;
    int t = threadIdx.x;
    float r = (5.0f / (float)(NT_ - 1)) * (float)k;
    float rs = fmaxf(r, 1e-9f);
    float inv = 1.0f / rs;
    float x = r * 0.2f;
    float x2 = x * x, x3 = x2 * x, x6 = x3 * x3, x7 = x6 * x, x8 = x7 * x;
    float fcv = 1.f - 28.f * x6 + 48.f * x7 - 21.f * x8;
    float scl = 0.63245553203367587f * inv * fcv;
    float ef[8];
    #pragma unroll
    for (int q = 0; q < 8; q++)
        ef[q] = scl * sinf(0.62831853071795865f * rs * (float)(q + 1));

    const float* r1  = Wc + OFF_R1T + l * 512;    // [64][8]
    const float* r2w = Wc + OFF_R2  + l * 4096;   // [64][64]
    const float* r3l = Wc + OFF_R3T + l * 10240;  // [32][5][64]
    if (t < 64) {
        float a = 0.f;
        #pragma unroll
        for (int q = 0; q < 8; q++) a += ef[q] * r1[t * 8 + q];
        h1s[t] = silu_f(a);
    }
    __syncthreads();
    if (t < 64) {
        float a = 0.f;
        for (int kk = 0; kk < 64; kk++) a += h1s[kk] * r2w[kk * 64 + t];
        h2s[t] = silu_f(a);
    }
    __syncthreads();
    if (t < 160) {
        int c = t / 5, p = t % 5;
        const float* rp = r3l + (c * 5 + p) * 64;
        float a = 0.f;
        for (int j = 0; j < 64; j++) a += h2s[j] * rp[j];
        tab[(((size_t)l * NT_ + k) * 32 + c) * 8 + p] = a;
    }
}

// ---- dst-sort build step 1: per-dst degree of ACTIVE edges (r < RCUT).
// Round-12: shifts stream (9.6MB) gated on shz (zero in this benchmark). ----
__global__ __launch_bounds__(256) void deg_kernel(const int* __restrict__ ei,
                                                  const float* __restrict__ posf,
                                                  const void* __restrict__ shifts,
                                                  const int* __restrict__ flags,
                                                  int* __restrict__ rp) {
    int e = blockIdx.x * 256 + threadIdx.x;
    int s = ei[e], d = ei[E_ + e];
    if (s < 0 || s >= N_ || d < 0 || d >= N_) return;
    float sx = 0.f, sy = 0.f, sz = 0.f;
    if (flags[O_SHZ]) {
        int isb = flags[O_FLAG];
        sx = ldi(shifts, e * 3 + 0, isb);
        sy = ldi(shifts, e * 3 + 1, isb);
        sz = ldi(shifts, e * 3 + 2, isb);
    }
    float vx = posf[d * 3 + 0] - posf[s * 3 + 0] + sx;
    float vy = posf[d * 3 + 1] - posf[s * 3 + 1] + sy;
    float vz = posf[d * 3 + 2] - posf[s * 3 + 2] + sz;
    if (vx * vx + vy * vy + vz * vz < 25.0f) atomicAdd(rp + d, 1);
}

// ---- step 2: multi-block exclusive scan (r11-proven) ----
__global__ __launch_bounds__(256) void scanA_kernel(const int* __restrict__ rp,
                                                    int* __restrict__ bsum) {
    __shared__ int red[256];
    int b = blockIdx.x, t = threadIdx.x;
    int base = b * SCB_ + t * 4;
    int s = 0;
    #pragma unroll
    for (int i = 0; i < 4; i++) { int idx = base + i; if (idx < N_) s += rp[idx]; }
    red[t] = s;
    __syncthreads();
    for (int off = 128; off > 0; off >>= 1) {
        if (t < off) red[t] += red[t + off];
        __syncthreads();
    }
    if (t == 0) bsum[b] = red[0];
}

__global__ __launch_bounds__(64) void scanB_kernel(int* __restrict__ bsum,
                                                   int* __restrict__ cnt) {
    int t = threadIdx.x;                      // single wave64
    int v = (t < NSB_) ? bsum[t] : 0;
    int inc = v;
    #pragma unroll
    for (int off = 1; off < 64; off <<= 1) {
        int u = __shfl_up(inc, off, 64);
        if (t >= off) inc += u;
    }
    if (t < NSB_) bsum[t] = inc - v;          // exclusive block offsets
    if (t == 63) cnt[0] = inc;                // grand total (lanes >= NSB_ add 0)
}

__global__ __launch_bounds__(256) void scanC_kernel(int* __restrict__ rp,
                                                    const int* __restrict__ bsum) {
    __shared__ int ps[256];
    int b = blockIdx.x, t = threadIdx.x;
    int base = b * SCB_ + t * 4;
    int v0 = 0, v1 = 0, v2 = 0, v3 = 0;
    if (base + 0 < N_) v0 = rp[base + 0];
    if (base + 1 < N_) v1 = rp[base + 1];
    if (base + 2 < N_) v2 = rp[base + 2];
    if (base + 3 < N_) v3 = rp[base + 3];
    int s = v0 + v1 + v2 + v3;
    ps[t] = s;
    __syncthreads();
    for (int off = 1; off < 256; off <<= 1) {
        int u = (t >= off) ? ps[t - off] : 0;
        __syncthreads();
        ps[t] += u;
        __syncthreads();
    }
    int run = bsum[b] + ((t == 0) ? 0 : ps[t - 1]);
    if (base + 0 < N_) { rp[base + 0] = run; run += v0; }
    if (base + 1 < N_) { rp[base + 1] = run; run += v1; }
    if (base + 2 < N_) { rp[base + 2] = run; run += v2; }
    if (base + 3 < N_) { rp[base + 3] = run; run += v3; }
}

// ---- step 3: counting-sort scatter; packed (src<<16|dst) + edge id; shz-gated ----
__global__ __launch_bounds__(256) void scatter_kernel(const int* __restrict__ ei,
                                                      const float* __restrict__ posf,
                                                      const void* __restrict__ shifts,
                                                      const int* __restrict__ flags,
                                                      int* __restrict__ rp,
                                                      unsigned* __restrict__ sdArr,
                                                      int* __restrict__ eidArr) {
    int e = blockIdx.x * 256 + threadIdx.x;
    int s = ei[e], d = ei[E_ + e];
    if (s < 0 || s >= N_ || d < 0 || d >= N_) return;
    float sx = 0.f, sy = 0.f, sz = 0.f;
    if (flags[O_SHZ]) {
        int isb = flags[O_FLAG];
        sx = ldi(shifts, e * 3 + 0, isb);
        sy = ldi(shifts, e * 3 + 1, isb);
        sz = ldi(shifts, e * 3 + 2, isb);
    }
    float vx = posf[d * 3 + 0] - posf[s * 3 + 0] + sx;
    float vy = posf[d * 3 + 1] - posf[s * 3 + 1] + sy;
    float vz = posf[d * 3 + 2] - posf[s * 3 + 2] + sz;
    if (vx * vx + vy * vy + vz * vz < 25.0f) {
        int pos = atomicAdd(rp + d, 1);
        sdArr[pos] = ((unsigned)s << 16) | (unsigned)d;   // N=50000 < 2^16
        eidArr[pos] = e;
    }
}

// segmented inclusive sum over the 16 groups of a wave (stride-4 lanes).
__device__ __forceinline__ float segsum16(float v, int lane, int g, int hdv) {
    #pragma unroll
    for (int s = 1; s < 16; s <<= 1) {
        float u = __shfl(v, (lane - 4 * s) & 63, 64);
        if (g - s >= hdv) v += u;
    }
    return v;
}

// ---- fused edge kernel, 4 lanes per edge, dst-sorted slots (r10/r11-proven).
// Round-12: template<VZ>. VZ=1 (layer 0): v-state is exactly zero and
// su = embup[spec[src]] (10 rows, L1-resident) -> NO sub/vub gathers
// (was 256B/edge = the entire 57MB FETCH), math reduces to w0*ss / w1*ss*Y.
// VZ=0 (layer 1): the full r10 path, unchanged. ----
template<int VZ>
__global__ __launch_bounds__(256, 4) void msg_kernel(const unsigned* __restrict__ sd,
                                                     const int* __restrict__ eidA,
                                                     const int* __restrict__ cnt,
                                                     const float* __restrict__ posf,
                                                     const void* __restrict__ shifts,
                                                     const int* __restrict__ flags,
                                                     const float* __restrict__ tab,
                                                     const bf16* __restrict__ sub,
                                                     const bf16* __restrict__ vub,
                                                     const int* __restrict__ spec,
                                                     const float* __restrict__ embup,
                                                     float* __restrict__ S,
                                                     float* __restrict__ V, int layer) {
    // XCD swizzle: within each 128-block super-tile, XCD k (= bid%8) gets a
    // CONTIGUOUS run of G=16 edge tiles. Bijective; identity on the tail.
    constexpr int G = 16, SUP = 8 * G;
    int bid = blockIdx.x;
    int nfull = ((int)gridDim.x / SUP) * SUP;
    int sbid = bid;
    if (bid < nfull) {
        int sup = bid / SUP, rr = bid % SUP;
        sbid = sup * SUP + (rr % 8) * G + (rr / 8);
    }

    int tid = threadIdx.x;
    int lane = tid & 63;
    int waveid = tid >> 6;
    int g = lane >> 2;                 // group within wave (0..15)
    int l = lane & 3;                  // lane within group (0..3)
    int total = cnt[0];
    int base = sbid * 64 + waveid * 16;
    if (base >= total) return;         // wave-uniform early out
    int i0 = base + g;
    bool valid = (i0 < total);
    int i = valid ? i0 : (total - 1);  // clamp tail; contribution zeroed via scale
    unsigned sdv = sd[i];
    int srcn = (int)(sdv >> 16), dstn = (int)(sdv & 0xFFFFu);
    float scale = valid ? 0.0625f : 0.0f;

    // ---- exact run topology (global, via sequential peeks) ----
    bool head_ex = valid && (i == 0 || (int)(sd[i - 1] & 0xFFFFu) != dstn);
    bool last_ex = valid && (i == total - 1 || (int)(sd[i + 1] & 0xFFFFu) != dstn);
    int dstx = __shfl(dstn, (lane + 4) & 63, 64);
    bool last_wt = (g == 15) || (dstx != dstn);     // within-tile run end (writer)
    int hv = head_ex ? g + 1 : 0;                   // max-scan of exact head pos+1
    #pragma unroll
    for (int s2 = 1; s2 < 16; s2 <<= 1) {
        int o = __shfl(hv, (lane - 4 * s2) & 63, 64);
        if (g >= s2) hv = max(hv, o);
    }
    int hdv = (hv > 0) ? hv - 1 : 0;
    bool complete = last_ex && (hv > 0);            // run fully inside this tile

    // per-edge state sources
    const unsigned short* sp = nullptr;
    const unsigned short* vp = nullptr;
    const float* eu = nullptr;
    unsigned short pf_s = 0, pf_v0 = 0, pf_v1 = 0, pf_v2 = 0;
    if constexpr (VZ) {
        eu = embup + (size_t)spec[srcn] * 32;       // 10-row L1 table
    } else {
        sp = (const unsigned short*)(sub + (size_t)srcn * 32 + l);
        vp = (const unsigned short*)(vub + (size_t)srcn * 96 + 3 * l);
        pf_s  = sp[0];
        pf_v0 = vp[0]; pf_v1 = vp[1]; pf_v2 = vp[2];
    }

    float vx = posf[dstn * 3 + 0] - posf[srcn * 3 + 0];
    float vy = posf[dstn * 3 + 1] - posf[srcn * 3 + 1];
    float vz = posf[dstn * 3 + 2] - posf[srcn * 3 + 2];
    if (flags[O_SHZ]) {                // shifts nonzero: rare fallback path
        int isb = flags[O_FLAG];
        int e = eidA[i];
        vx += ldi(shifts, e * 3 + 0, isb);
        vy += ldi(shifts, e * 3 + 1, isb);
        vz += ldi(shifts, e * 3 + 2, isb);
    }
    float r2 = vx * vx + vy * vy + vz * vz;
    float r = sqrtf(r2);
    float rs = fmaxf(r, 1e-9f);
    float inv = 1.0f / rs;
    float Yx = vx * inv, Yy = vy * inv, Yz = vz * inv;

    // table coordinates: r in [0,5) -> k0 in [0,510], frac f
    float tpos = r * ((float)(NT_ - 1) / 5.0f);
    int k0 = min((int)tpos, NT_ - 2);
    float f = tpos - (float)k0;
    const float* t0 = tab + ((size_t)layer * NT_ + k0) * 256;   // 32 ch * 8 floats
    const float* t1 = t0 + 256;

    float* Sd = S + (size_t)dstn * 32;
    float* Vd = V + (size_t)dstn * 96;

    if constexpr (VZ) {
        // ---- layer-0 path: ss from L1 table, v=0 => only w0,w1 matter ----
        #pragma unroll 1
        for (int c4 = 0; c4 < 8; c4++) {
            const int c = 4 * c4 + l;
            float ss = eu[c];
            float2 wa2 = *(const float2*)(t0 + c * 8);
            float2 wb2 = *(const float2*)(t1 + c * 8);
            float w0 = wa2.x + f * (wb2.x - wa2.x);
            float w1 = wa2.y + f * (wb2.y - wa2.y);
            float ms = (w0 * ss) * scale;
            float w1s = (w1 * ss) * scale;
            float mx = w1s * Yx;
            float my = w1s * Yy;
            float mz = w1s * Yz;
            ms = segsum16(ms, lane, g, hdv);
            mx = segsum16(mx, lane, g, hdv);
            my = segsum16(my, lane, g, hdv);
            mz = segsum16(mz, lane, g, hdv);
            if (last_wt) {
                if (complete) {
                    Sd[c] = ms;
                    Vd[c * 3 + 0] = mx;
                    Vd[c * 3 + 1] = my;
                    Vd[c * 3 + 2] = mz;
                } else {
                    atomicAdd(Sd + c, ms);
                    atomicAdd(Vd + c * 3 + 0, mx);
                    atomicAdd(Vd + c * 3 + 1, my);
                    atomicAdd(Vd + c * 3 + 2, mz);
                }
            }
        }
    } else {
        // ---- full path (layer 1): r10-proven rolling-prefetch schedule ----
        float4 pf_wa = *(const float4*)(t0 + l * 8);
        float  pf_wa4 = (t0 + l * 8)[4];
        float4 pf_wb = *(const float4*)(t1 + l * 8);
        float  pf_wb4 = (t1 + l * 8)[4];

        #pragma unroll 1
        for (int c4 = 0; c4 < 8; c4++) {
            float ss  = b2f(pf_s);
            float vvx = b2f(pf_v0);
            float vvy = b2f(pf_v1);
            float vvz = b2f(pf_v2);
            float4 wa = pf_wa; float wa4 = pf_wa4;
            float4 wb = pf_wb; float wb4 = pf_wb4;

            // prefetch next chunk (states + table); c4=7 prefetch lands in-arena
            pf_s  = sp[4 * c4 + 4];
            pf_v0 = vp[12 * c4 + 12];
            pf_v1 = vp[12 * c4 + 13];
            pf_v2 = vp[12 * c4 + 14];
            int noff = (4 * c4 + 4 + l) * 8;
            pf_wa = *(const float4*)(t0 + noff);
            pf_wa4 = (t0 + noff)[4];
            pf_wb = *(const float4*)(t1 + noff);
            pf_wb4 = (t1 + noff)[4];

            float w0 = wa.x + f * (wb.x - wa.x);
            float w1 = wa.y + f * (wb.y - wa.y);
            float w2 = wa.z + f * (wb.z - wa.z);
            float w3 = wa.w + f * (wb.w - wa.w);
            float w4 = wa4 + f * (wb4 - wa4);

            const int c = 4 * c4 + l;
            float dt = vvx * Yx + vvy * Yy + vvz * Yz;
            float cx = vvy * Yz - vvz * Yy;
            float cy = vvz * Yx - vvx * Yz;
            float cz = vvx * Yy - vvy * Yx;
            float ms = (w0 * ss + w3 * dt) * scale;
            float mx = (w1 * ss * Yx + w2 * vvx + w4 * cx) * scale;
            float my = (w1 * ss * Yy + w2 * vvy + w4 * cy) * scale;
            float mz = (w1 * ss * Yz + w2 * vvz + w4 * cz) * scale;

            ms = segsum16(ms, lane, g, hdv);
            mx = segsum16(mx, lane, g, hdv);
            my = segsum16(my, lane, g, hdv);
            mz = segsum16(mz, lane, g, hdv);
            if (last_wt) {
                if (complete) {
                    Sd[c] = ms;
                    Vd[c * 3 + 0] = mx;
                    Vd[c * 3 + 1] = my;
                    Vd[c * 3 + 2] = mz;
                } else {
                    atomicAdd(Sd + c, ms);
                    atomicAdd(Vd + c * 3 + 0, mx);
                    atomicAdd(Vd + c * 3 + 1, my);
                    atomicAdd(Vd + c * 3 + 2, mz);
                }
            }
        }
    }
}

// ---- per-node post: out/skip/product/linear, writes invariants + new s,v in-place.
// When fuse!=0 also computes next layer's "up" (su/vu) from the fresh s,v. ----
__global__ __launch_bounds__(256) void post_kernel(const float* __restrict__ Wc,
                                                   const float* __restrict__ Sb,
                                                   const float* __restrict__ Vb,
                                                   float* __restrict__ s,
                                                   bf16* __restrict__ vbst,
                                                   const int* __restrict__ spec,
                                                   float* __restrict__ out,
                                                   bf16* __restrict__ su,
                                                   bf16* __restrict__ vu,
                                                   int fuse, int layer) {
    __shared__ float A_s[8][32];
    __shared__ float A_v[8][96];
    __shared__ float B_s[8][32];
    __shared__ float B_v[8][96];
    int tid = threadIdx.x;
    int nl = tid >> 5, d = tid & 31;
    int n = blockIdx.x * 8 + nl;
    A_s[nl][d]      = Sb[n * 32 + d];
    A_v[nl][d]      = Vb[n * 96 + d];
    A_v[nl][d + 32] = Vb[n * 96 + d + 32];
    A_v[nl][d + 64] = Vb[n * 96 + d + 64];
    B_s[nl][d]      = s[n * 32 + d];
    B_v[nl][d]      = (float)vbst[n * 96 + d];
    B_v[nl][d + 32] = (float)vbst[n * 96 + d + 32];
    B_v[nl][d + 64] = (float)vbst[n * 96 + d + 64];
    __syncthreads();

    int z = spec[n];
    const float* wos = Wc + OFF_OUTS + layer * 1024;
    const float* wov = Wc + OFF_OUTV + layer * 1024;
    const float* wss = Wc + OFF_SCS + (layer * Z_ + z) * 1024;
    const float* wsv = Wc + OFF_SCV + (layer * Z_ + z) * 1024;
    float s2 = 0.f, v20 = 0.f, v21 = 0.f, v22 = 0.f;
    float scs = 0.f, scv0 = 0.f, scv1 = 0.f, scv2 = 0.f;
    #pragma unroll 8
    for (int c = 0; c < 32; c++) {
        float wo = wos[c * 32 + d], wv = wov[c * 32 + d];
        float wa = wss[c * 32 + d], wb = wsv[c * 32 + d];
        s2  += A_s[nl][c] * wo;
        v20 += A_v[nl][c * 3 + 0] * wv;
        v21 += A_v[nl][c * 3 + 1] * wv;
        v22 += A_v[nl][c * 3 + 2] * wv;
        scs  += B_s[nl][c] * wa;
        scv0 += B_v[nl][c * 3 + 0] * wb;
        scv1 += B_v[nl][c * 3 + 1] * wb;
        scv2 += B_v[nl][c * 3 + 2] * wb;
    }
    const float* wp = Wc + OFF_WP + (layer * Z_ + z) * 160;
    float we0 = wp[d], we1 = wp[32 + d], we2 = wp[64 + d], we3 = wp[96 + d], we4 = wp[128 + d];
    float ps = we0 * s2 + we1 * s2 * s2 + we2 * (v20 * v20 + v21 * v21 + v22 * v22);
    float pv0 = we3 * v20 + we4 * s2 * v20;
    float pv1 = we3 * v21 + we4 * s2 * v21;
    float pv2 = we3 * v22 + we4 * s2 * v22;
    __syncthreads();
    A_s[nl][d] = ps;
    A_v[nl][d * 3 + 0] = pv0;
    A_v[nl][d * 3 + 1] = pv1;
    A_v[nl][d * 3 + 2] = pv2;
    __syncthreads();
    const float* wls = Wc + OFF_LINS + layer * 1024;
    const float* wlv = Wc + OFF_LINV + layer * 1024;
    float sn = scs, vn0 = scv0, vn1 = scv1, vn2 = scv2;
    #pragma unroll 8
    for (int c = 0; c < 32; c++) {
        float wl = wls[c * 32 + d], w2_ = wlv[c * 32 + d];
        sn  += A_s[nl][c] * wl;
        vn0 += A_v[nl][c * 3 + 0] * w2_;
        vn1 += A_v[nl][c * 3 + 1] * w2_;
        vn2 += A_v[nl][c * 3 + 2] * w2_;
    }
    s[n * 32 + d] = sn;
    out[(size_t)n * 64 + layer * 32 + d] = sn;   // fp32 output (verified round 5)
    vbst[n * 96 + d * 3 + 0] = __float2bfloat16(vn0);
    vbst[n * 96 + d * 3 + 1] = __float2bfloat16(vn1);
    vbst[n * 96 + d * 3 + 2] = __float2bfloat16(vn2);

    if (fuse) {
        __syncthreads();
        B_s[nl][d]         = sn;
        B_v[nl][d * 3 + 0] = vn0;
        B_v[nl][d * 3 + 1] = vn1;
        B_v[nl][d * 3 + 2] = vn2;
        __syncthreads();
        const float* wus = Wc + OFF_UPS + (layer + 1) * 1024;
        const float* wuv = Wc + OFF_UPV + (layer + 1) * 1024;
        float a0 = 0.f, b0 = 0.f, b1 = 0.f, b2 = 0.f;
        #pragma unroll 8
        for (int c = 0; c < 32; c++) {
            float wS = wus[c * 32 + d], wV = wuv[c * 32 + d];
            a0 += B_s[nl][c] * wS;
            b0 += B_v[nl][c * 3 + 0] * wV;
            b1 += B_v[nl][c * 3 + 1] * wV;
            b2 += B_v[nl][c * 3 + 2] * wV;
        }
        su[n * 32 + d] = __float2bfloat16(a0);
        vu[n * 96 + d * 3 + 0] = __float2bfloat16(b0);
        vu[n * 96 + d * 3 + 1] = __float2bfloat16(b1);
        vu[n * 96 + d * 3 + 2] = __float2bfloat16(b2);
    }
}

// Host-side: resolve input pointers by element count (robust to harness input
// ordering). Greedy first-unused match preserves relative order within equal
// sizes, so if the harness order == reference dict order this is the identity.
static void resolve_inputs(const int* in_sizes, int n_in, int idx[17]) {
    const int want[17] = {150000, 500000, 2400000, 320, 2048, 2048, 1024, 8192,
                          20480, 2048, 2048, 20480, 20480, 3200, 2048, 2048, 1600000};
    for (int k = 0; k < 17; k++) idx[k] = k;   // default identity
    if (!in_sizes || n_in < 17) return;
    bool used[64];
    for (int i = 0; i < 64; i++) used[i] = false;
    int tmp[17];
    for (int k = 0; k < 17; k++) {
        int found = -1;
        for (int i = 0; i < n_in && i < 64; i++) {
            if (!used[i] && in_sizes[i] == want[k]) { found = i; break; }
        }
        if (found < 0) return;               // sizes don't match expectation: keep identity
        used[found] = true;
        tmp[k] = found;
    }
    for (int k = 0; k < 17; k++) idx[k] = tmp[k];
}

extern "C" void kernel_launch(void* const* d_in, const int* in_sizes, int n_in,
                              void* d_out, int out_size, void* d_ws, size_t ws_size,
                              hipStream_t stream) {
    (void)out_size; (void)ws_size;
    int idx[17];
    resolve_inputs(in_sizes, n_in, idx);

    const void* pos    = d_in[idx[0]];
    const void* attrs  = d_in[idx[1]];
    const void* shifts = d_in[idx[2]];
    const int*  ei     = (const int*)d_in[idx[16]];
    float* out = (float*)d_out;

    int*   I = (int*)d_ws;
    float* W = (float*)d_ws;

    hipMemsetAsync(I, 0, 64 * sizeof(int), stream);                             // cnt + flags
    hipMemsetAsync(I + O_ROWP, 0, 50048 * sizeof(int), stream);                 // degrees
    hipMemsetAsync(W + O_VB, 0, (size_t)N_ * C_ * 3 * sizeof(bf16), stream);    // v state = 0

    detect_kernel<<<1, 256, 0, stream>>>((const unsigned*)attrs, I + O_FLAG);
    shiftchk_kernel<<<2048, 256, 0, stream>>>((const unsigned*)shifts, I + O_FLAG, I + O_SHZ);

    ConvArgs ca;
    for (int k = 0; k < 13; k++) ca.p[k] = d_in[idx[3 + k]];
    convert_kernel<<<(W_TOTAL + 255) / 256, 256, 0, stream>>>(ca, I + O_FLAG, W + O_W);
    posconv_kernel<<<(N_ * 3 + 255) / 256, 256, 0, stream>>>(pos, I + O_FLAG, W + O_POSF);
    spec_kernel<<<(N_ + 255) / 256, 256, 0, stream>>>(attrs, I + O_FLAG, I + O_SPEC);
    embup_kernel<<<1, 320, 0, stream>>>(W + O_W, W + O_EMBU);
    sinit_kernel<<<(N_ * C_) / 256, 256, 0, stream>>>(W + O_W, I + O_SPEC, W + O_S);

    // radial w-table (both layers; needs converted weights)
    tab_kernel<<<2 * NT_, 256, 0, stream>>>(W + O_W, W + O_TAB);

    // one-time dst-sorted active-edge list (counting sort; graph static across layers)
    deg_kernel<<<E_ / 256, 256, 0, stream>>>(ei, W + O_POSF, shifts, I, I + O_ROWP);
    scanA_kernel<<<NSB_, 256, 0, stream>>>(I + O_ROWP, I + O_BSUM);
    scanB_kernel<<<1, 64, 0, stream>>>(I + O_BSUM, I + O_CNT);
    scanC_kernel<<<NSB_, 256, 0, stream>>>(I + O_ROWP, I + O_BSUM);
    scatter_kernel<<<E_ / 256, 256, 0, stream>>>(ei, W + O_POSF, shifts, I,
                                                 I + O_ROWP, (unsigned*)(I + O_SD),
                                                 I + O_EID2);

    for (int l = 0; l < 2; l++) {
        hipMemsetAsync(W + O_SS, 0, (size_t)N_ * C_ * 4 * sizeof(float), stream);  // SS+VV
        if (l == 0)
            msg_kernel<1><<<(E_ + 63) / 64, 256, 0, stream>>>(
                (const unsigned*)(I + O_SD), I + O_EID2, I + O_CNT,
                W + O_POSF, shifts, I, W + O_TAB,
                (const bf16*)(W + O_SUB), (const bf16*)(W + O_VUB),
                I + O_SPEC, W + O_EMBU, W + O_SS, W + O_VV, l);
        else
            msg_kernel<0><<<(E_ + 63) / 64, 256, 0, stream>>>(
                (const unsigned*)(I + O_SD), I + O_EID2, I + O_CNT,
                W + O_POSF, shifts, I, W + O_TAB,
                (const bf16*)(W + O_SUB), (const bf16*)(W + O_VUB),
                I + O_SPEC, W + O_EMBU, W + O_SS, W + O_VV, l);
        post_kernel<<<N_ / 8, 256, 0, stream>>>(W + O_W, W + O_SS, W + O_VV,
                                                W + O_S, (bf16*)(W + O_VB),
                                                I + O_SPEC, out,
                                                (bf16*)(W + O_SUB), (bf16*)(W + O_VUB),
                                                (l == 0) ? 1 : 0, l);
    }
}

// Round 13
// 444.240 us; speedup vs baseline: 1.6617x; 1.0043x over previous
//
#include <hip/hip_runtime.h>
#include <hip/hip_bf16.h>

typedef __hip_bfloat16 bf16;

// Problem constants
constexpr int N_ = 50000;
constexpr int E_ = 800000;
constexpr int C_ = 32;
constexpr int Z_ = 10;

// fp32 weight arena offsets (floats)
constexpr int OFF_EMB  = 0;                    // [Z][C]          320
constexpr int OFF_UPS  = 320;                  // [L][C][C]       2048
constexpr int OFF_UPV  = OFF_UPS + 2048;       // [L][C][C]       2048
constexpr int OFF_R1T  = OFF_UPV + 2048;       // [L][64][8]  (transposed)  1024
constexpr int OFF_R2   = OFF_R1T + 1024;       // [L][64][64]     8192
constexpr int OFF_R3T  = OFF_R2 + 8192;        // [L][32][5][64] (c-major) 20480
constexpr int OFF_OUTS = OFF_R3T + 20480;      // [L][C][C]       2048
constexpr int OFF_OUTV = OFF_OUTS + 2048;      // [L][C][C]       2048
constexpr int OFF_SCS  = OFF_OUTV + 2048;      // [L][Z][C][C]    20480
constexpr int OFF_SCV  = OFF_SCS + 20480;      // [L][Z][C][C]    20480
constexpr int OFF_WP   = OFF_SCV + 20480;      // [L][Z][5][C]    3200
constexpr int OFF_LINS = OFF_WP + 3200;        // [L][C][C]       2048
constexpr int OFF_LINV = OFF_LINS + 2048;      // [L][C][C]       2048
constexpr int W_TOTAL  = OFF_LINV + 2048;      // 86464

// workspace layout, in 4-byte words (within proven 56.41 MiB arena)
constexpr size_t O_CNT  = 0;                   // int: active edge count
constexpr size_t O_FLAG = 1;                   // int: 1 => float inputs are bf16
constexpr size_t O_SHZ  = 2;                   // int: 1 => shifts are NONZERO
constexpr size_t O_BSUM = 8;                   // 49 ints: scan block sums (in zeroed 64)
constexpr size_t O_SPEC = 64;                  // N ints (padded 50048)
constexpr size_t O_SD   = 50112;               // 250000 u32: (src<<16)|dst, dst-sorted
constexpr size_t O_EID2 = 300112;              // 250000 int: original edge id per slot
                                               //   (consumed only when shifts nonzero)
constexpr size_t O_TAB  = 550112;              // [L=2][512][32][8] fp32 w-table, 262144
constexpr size_t O_EMBU = 812256;              // [Z][C] fp32 embup = emb@Wus0, 320 words
constexpr size_t O_POSF = 850112;              // N*3 fp32 (padded 150016)
constexpr size_t O_W    = 1000128;             // W_TOTAL fp32
constexpr size_t O_S    = 1086592;             // N*C fp32 (state s)
constexpr size_t O_VB   = 2686592;             // N*C*3 bf16 (state v, 2400000 words)
constexpr size_t O_PK   = 5086592;             // N*128 bf16 PACKED up-state (3.2M words):
                                               //   pk[n][0..31]=su, pk[n][32..127]=vu
                                               //   (one 256B row = 4 contiguous lines/edge;
                                               //   reuses the old SUB+VUB region exactly)
constexpr size_t O_SS   = 8286592;             // N*C fp32   (S accum)
constexpr size_t O_VV   = 9886592;             // N*C*3 fp32 (V accum) -> ends 14686592
constexpr size_t O_ROWP = 14686592;            // N ints (padded 50048): rowptr (destructive)

constexpr int NT_ = 512;                       // radial table points over r in [0,5]
constexpr int SCB_ = 1024;                     // scan: elements per block
constexpr int NSB_ = (N_ + SCB_ - 1) / SCB_;   // 49 scan blocks (<= 64 for scanB wave)

struct ConvArgs { const void* p[13]; };

// dual-dtype input load: isb is wave-uniform => scalar branch
__device__ __forceinline__ float ldi(const void* p, int i, int isb) {
    if (isb) return (float)((const bf16*)p)[i];
    return ((const float*)p)[i];
}
__device__ __forceinline__ float b2f(unsigned short u) {   // bf16 bits -> float
    union { unsigned x; float f; } v; v.x = ((unsigned)u) << 16; return v.f;
}

// ---- dtype detection on node_attrs (one-hot): word 0x00003F80 occurs only if bf16 ----
__global__ __launch_bounds__(256) void detect_kernel(const unsigned* __restrict__ a,
                                                     int* __restrict__ flag) {
    int t = threadIdx.x;
    int hit = 0;
    for (int i = t; i < 4096; i += 256) hit |= (a[i] == 0x00003F80u) ? 1 : 0;
    if (hit) atomicOr(flag, 1);
}

// ---- shifts nonzero detection (any nonzero word -> shz=1). Runs after detect. ----
__global__ __launch_bounds__(256) void shiftchk_kernel(const unsigned* __restrict__ sh,
                                                       const int* __restrict__ flag,
                                                       int* __restrict__ shz) {
    int words = (*flag) ? (E_ * 3 / 2) : (E_ * 3);
    int t = blockIdx.x * 256 + threadIdx.x;
    int hit = 0;
    for (int i = t; i < words; i += 2048 * 256) hit |= (sh[i] != 0u) ? 1 : 0;
    if (hit) atomicOr(shz, 1);
}

// ---- weight conversion (-> fp32, with R1/R3 transposes) ----
__global__ __launch_bounds__(256) void convert_kernel(ConvArgs a, const int* __restrict__ flag,
                                                      float* __restrict__ Wc) {
    int t = blockIdx.x * 256 + threadIdx.x;
    if (t >= W_TOTAL) return;
    int isb = *flag;
    int u = t;
    if (u < 320)  { Wc[OFF_EMB + u] = ldi(a.p[0], u, isb); return; }  u -= 320;
    if (u < 2048) { Wc[OFF_UPS + u] = ldi(a.p[1], u, isb); return; }  u -= 2048;
    if (u < 2048) { Wc[OFF_UPV + u] = ldi(a.p[2], u, isb); return; }  u -= 2048;
    if (u < 1024) {                       // R1 [L][8][64] -> R1T [L][64][8]
        int l = u >> 9, r = u & 511, j = r >> 3, k = r & 7;
        Wc[OFF_R1T + u] = ldi(a.p[3], l * 512 + k * 64 + j, isb); return;
    }  u -= 1024;
    if (u < 8192) { Wc[OFF_R2 + u] = ldi(a.p[4], u, isb); return; }   u -= 8192;
    if (u < 20480) {                      // R3 [L][64][160] -> R3T [L][32][5][64] (c-major)
        int l = u / 10240, r = u % 10240, c = r / 320, r2 = r % 320, p = r2 / 64, j = r2 % 64;
        Wc[OFF_R3T + u] = ldi(a.p[5], l * 10240 + j * 160 + p * 32 + c, isb); return;
    }  u -= 20480;
    if (u < 2048)  { Wc[OFF_OUTS + u] = ldi(a.p[6], u, isb);  return; } u -= 2048;
    if (u < 2048)  { Wc[OFF_OUTV + u] = ldi(a.p[7], u, isb);  return; } u -= 2048;
    if (u < 20480) { Wc[OFF_SCS  + u] = ldi(a.p[8], u, isb);  return; } u -= 20480;
    if (u < 20480) { Wc[OFF_SCV  + u] = ldi(a.p[9], u, isb);  return; } u -= 20480;
    if (u < 3200)  { Wc[OFF_WP   + u] = ldi(a.p[10], u, isb); return; } u -= 3200;
    if (u < 2048)  { Wc[OFF_LINS + u] = ldi(a.p[11], u, isb); return; } u -= 2048;
    Wc[OFF_LINV + u] = ldi(a.p[12], u, isb);
}

// ---- positions -> fp32 ----
__global__ __launch_bounds__(256) void posconv_kernel(const void* __restrict__ pos,
                                                      const int* __restrict__ flag,
                                                      float* __restrict__ posf) {
    int t = blockIdx.x * 256 + threadIdx.x;
    if (t >= N_ * 3) return;
    posf[t] = ldi(pos, t, *flag);
}

// ---- species from one-hot ----
__global__ __launch_bounds__(256) void spec_kernel(const void* __restrict__ attrs,
                                                   const int* __restrict__ flag,
                                                   int* __restrict__ spec) {
    int n = blockIdx.x * 256 + threadIdx.x;
    if (n >= N_) return;
    int isb = *flag;
    int z = 0;
    #pragma unroll
    for (int zz = 0; zz < Z_; zz++)
        if (ldi(attrs, n * Z_ + zz, isb) > 0.5f) z = zz;
    spec[n] = z;
}

// ---- embup[z][d] = sum_c emb[z][c] * Wus0[c][d] (layer-0 su lookup table) ----
__global__ __launch_bounds__(320) void embup_kernel(const float* __restrict__ Wc,
                                                    float* __restrict__ embup) {
    int t = threadIdx.x;
    if (t >= 320) return;
    int z = t >> 5, d = t & 31;
    float a = 0.f;
    #pragma unroll 8
    for (int c = 0; c < 32; c++)
        a += Wc[OFF_EMB + z * 32 + c] * Wc[OFF_UPS + c * 32 + d];
    embup[t] = a;
}

// ---- s init: s = emb[spec] only ----
__global__ __launch_bounds__(256) void sinit_kernel(const float* __restrict__ Wc,
                                                    const int* __restrict__ spec,
                                                    float* __restrict__ s) {
    int t = blockIdx.x * 256 + threadIdx.x;   // N*C threads
    int n = t >> 5, c = t & 31;
    s[t] = Wc[OFF_EMB + spec[n] * C_ + c];
}

__device__ __forceinline__ float silu_f(float a) {
    return a / (1.f + __expf(-a));
}

// ---- radial w-table build: tab[l][k][c][8] = (h2(r_k) @ R3T)[c][p], p in 0..4 ----
__global__ __launch_bounds__(256) void tab_kernel(const float* __restrict__ Wc,
                                                  float* __restrict__ tab) {
    __shared__ float h1s[64];
    __shared__ float h2s[64];
    int bk = blockIdx.x;               // 0..1023 = l*512 + k
    int l = bk >> 9, k = bk & 511;
    int t = threadIdx.x;
    float r = (5.0f / (float)(NT_ - 1)) * (float)k;
    float rs = fmaxf(r, 1e-9f);
    float inv = 1.0f / rs;
    float x = r * 0.2f;
    float x2 = x * x, x3 = x2 * x, x6 = x3 * x3, x7 = x6 * x, x8 = x7 * x;
    float fcv = 1.f - 28.f * x6 + 48.f * x7 - 21.f * x8;
    float scl = 0.63245553203367587f * inv * fcv;
    float ef[8];
    #pragma unroll
    for (int q = 0; q < 8; q++)
        ef[q] = scl * sinf(0.62831853071795865f * rs * (float)(q + 1));

    const float* r1  = Wc + OFF_R1T + l * 512;    // [64][8]
    const float* r2w = Wc + OFF_R2  + l * 4096;   // [64][64]
    const float* r3l = Wc + OFF_R3T + l * 10240;  // [32][5][64]
    if (t < 64) {
        float a = 0.f;
        #pragma unroll
        for (int q = 0; q < 8; q++) a += ef[q] * r1[t * 8 + q];
        h1s[t] = silu_f(a);
    }
    __syncthreads();
    if (t < 64) {
        float a = 0.f;
        for (int kk = 0; kk < 64; kk++) a += h1s[kk] * r2w[kk * 64 + t];
        h2s[t] = silu_f(a);
    }
    __syncthreads();
    if (t < 160) {
        int c = t / 5, p = t % 5;
        const float* rp = r3l + (c * 5 + p) * 64;
        float a = 0.f;
        for (int j = 0; j < 64; j++) a += h2s[j] * rp[j];
        tab[(((size_t)l * NT_ + k) * 32 + c) * 8 + p] = a;
    }
}

// ---- dst-sort build step 1: per-dst degree of ACTIVE edges; shz-gated shifts ----
__global__ __launch_bounds__(256) void deg_kernel(const int* __restrict__ ei,
                                                  const float* __restrict__ posf,
                                                  const void* __restrict__ shifts,
                                                  const int* __restrict__ flags,
                                                  int* __restrict__ rp) {
    int e = blockIdx.x * 256 + threadIdx.x;
    int s = ei[e], d = ei[E_ + e];
    if (s < 0 || s >= N_ || d < 0 || d >= N_) return;
    float sx = 0.f, sy = 0.f, sz = 0.f;
    if (flags[O_SHZ]) {
        int isb = flags[O_FLAG];
        sx = ldi(shifts, e * 3 + 0, isb);
        sy = ldi(shifts, e * 3 + 1, isb);
        sz = ldi(shifts, e * 3 + 2, isb);
    }
    float vx = posf[d * 3 + 0] - posf[s * 3 + 0] + sx;
    float vy = posf[d * 3 + 1] - posf[s * 3 + 1] + sy;
    float vz = posf[d * 3 + 2] - posf[s * 3 + 2] + sz;
    if (vx * vx + vy * vy + vz * vz < 25.0f) atomicAdd(rp + d, 1);
}

// ---- step 2: multi-block exclusive scan (r11-proven) ----
__global__ __launch_bounds__(256) void scanA_kernel(const int* __restrict__ rp,
                                                    int* __restrict__ bsum) {
    __shared__ int red[256];
    int b = blockIdx.x, t = threadIdx.x;
    int base = b * SCB_ + t * 4;
    int s = 0;
    #pragma unroll
    for (int i = 0; i < 4; i++) { int idx = base + i; if (idx < N_) s += rp[idx]; }
    red[t] = s;
    __syncthreads();
    for (int off = 128; off > 0; off >>= 1) {
        if (t < off) red[t] += red[t + off];
        __syncthreads();
    }
    if (t == 0) bsum[b] = red[0];
}

__global__ __launch_bounds__(64) void scanB_kernel(int* __restrict__ bsum,
                                                   int* __restrict__ cnt) {
    int t = threadIdx.x;                      // single wave64
    int v = (t < NSB_) ? bsum[t] : 0;
    int inc = v;
    #pragma unroll
    for (int off = 1; off < 64; off <<= 1) {
        int u = __shfl_up(inc, off, 64);
        if (t >= off) inc += u;
    }
    if (t < NSB_) bsum[t] = inc - v;          // exclusive block offsets
    if (t == 63) cnt[0] = inc;                // grand total (lanes >= NSB_ add 0)
}

__global__ __launch_bounds__(256) void scanC_kernel(int* __restrict__ rp,
                                                    const int* __restrict__ bsum) {
    __shared__ int ps[256];
    int b = blockIdx.x, t = threadIdx.x;
    int base = b * SCB_ + t * 4;
    int v0 = 0, v1 = 0, v2 = 0, v3 = 0;
    if (base + 0 < N_) v0 = rp[base + 0];
    if (base + 1 < N_) v1 = rp[base + 1];
    if (base + 2 < N_) v2 = rp[base + 2];
    if (base + 3 < N_) v3 = rp[base + 3];
    int s = v0 + v1 + v2 + v3;
    ps[t] = s;
    __syncthreads();
    for (int off = 1; off < 256; off <<= 1) {
        int u = (t >= off) ? ps[t - off] : 0;
        __syncthreads();
        ps[t] += u;
        __syncthreads();
    }
    int run = bsum[b] + ((t == 0) ? 0 : ps[t - 1]);
    if (base + 0 < N_) { rp[base + 0] = run; run += v0; }
    if (base + 1 < N_) { rp[base + 1] = run; run += v1; }
    if (base + 2 < N_) { rp[base + 2] = run; run += v2; }
    if (base + 3 < N_) { rp[base + 3] = run; run += v3; }
}

// ---- step 3: counting-sort scatter; packed (src<<16|dst) + edge id; shz-gated ----
__global__ __launch_bounds__(256) void scatter_kernel(const int* __restrict__ ei,
                                                      const float* __restrict__ posf,
                                                      const void* __restrict__ shifts,
                                                      const int* __restrict__ flags,
                                                      int* __restrict__ rp,
                                                      unsigned* __restrict__ sdArr,
                                                      int* __restrict__ eidArr) {
    int e = blockIdx.x * 256 + threadIdx.x;
    int s = ei[e], d = ei[E_ + e];
    if (s < 0 || s >= N_ || d < 0 || d >= N_) return;
    float sx = 0.f, sy = 0.f, sz = 0.f;
    if (flags[O_SHZ]) {
        int isb = flags[O_FLAG];
        sx = ldi(shifts, e * 3 + 0, isb);
        sy = ldi(shifts, e * 3 + 1, isb);
        sz = ldi(shifts, e * 3 + 2, isb);
    }
    float vx = posf[d * 3 + 0] - posf[s * 3 + 0] + sx;
    float vy = posf[d * 3 + 1] - posf[s * 3 + 1] + sy;
    float vz = posf[d * 3 + 2] - posf[s * 3 + 2] + sz;
    if (vx * vx + vy * vy + vz * vz < 25.0f) {
        int pos = atomicAdd(rp + d, 1);
        sdArr[pos] = ((unsigned)s << 16) | (unsigned)d;   // N=50000 < 2^16
        eidArr[pos] = e;
    }
}

// segmented inclusive sum over the 16 groups of a wave (stride-4 lanes).
__device__ __forceinline__ float segsum16(float v, int lane, int g, int hdv) {
    #pragma unroll
    for (int s = 1; s < 16; s <<= 1) {
        float u = __shfl(v, (lane - 4 * s) & 63, 64);
        if (g - s >= hdv) v += u;
    }
    return v;
}

// ---- fused edge kernel, 4 lanes per edge, dst-sorted slots.
// Round-13: VZ=0 path reads the PACKED per-node up-state row pk[n][128]
// (su[0..31] ++ vu[32..127], bf16) — one 256B row = 4 CONTIGUOUS cache lines
// per edge gather (was sub+vub in two arrays 6.4MB apart = two DRAM page
// streams). Bytes unchanged; DRAM row locality improves. VZ=1 unchanged. ----
template<int VZ>
__global__ __launch_bounds__(256, 4) void msg_kernel(const unsigned* __restrict__ sd,
                                                     const int* __restrict__ eidA,
                                                     const int* __restrict__ cnt,
                                                     const float* __restrict__ posf,
                                                     const void* __restrict__ shifts,
                                                     const int* __restrict__ flags,
                                                     const float* __restrict__ tab,
                                                     const unsigned short* __restrict__ pk,
                                                     const int* __restrict__ spec,
                                                     const float* __restrict__ embup,
                                                     float* __restrict__ S,
                                                     float* __restrict__ V, int layer) {
    // XCD swizzle: within each 128-block super-tile, XCD k (= bid%8) gets a
    // CONTIGUOUS run of G=16 edge tiles. Bijective; identity on the tail.
    constexpr int G = 16, SUP = 8 * G;
    int bid = blockIdx.x;
    int nfull = ((int)gridDim.x / SUP) * SUP;
    int sbid = bid;
    if (bid < nfull) {
        int sup = bid / SUP, rr = bid % SUP;
        sbid = sup * SUP + (rr % 8) * G + (rr / 8);
    }

    int tid = threadIdx.x;
    int lane = tid & 63;
    int waveid = tid >> 6;
    int g = lane >> 2;                 // group within wave (0..15)
    int l = lane & 3;                  // lane within group (0..3)
    int total = cnt[0];
    int base = sbid * 64 + waveid * 16;
    if (base >= total) return;         // wave-uniform early out
    int i0 = base + g;
    bool valid = (i0 < total);
    int i = valid ? i0 : (total - 1);  // clamp tail; contribution zeroed via scale
    unsigned sdv = sd[i];
    int srcn = (int)(sdv >> 16), dstn = (int)(sdv & 0xFFFFu);
    float scale = valid ? 0.0625f : 0.0f;

    // ---- exact run topology (global, via sequential peeks) ----
    bool head_ex = valid && (i == 0 || (int)(sd[i - 1] & 0xFFFFu) != dstn);
    bool last_ex = valid && (i == total - 1 || (int)(sd[i + 1] & 0xFFFFu) != dstn);
    int dstx = __shfl(dstn, (lane + 4) & 63, 64);
    bool last_wt = (g == 15) || (dstx != dstn);     // within-tile run end (writer)
    int hv = head_ex ? g + 1 : 0;                   // max-scan of exact head pos+1
    #pragma unroll
    for (int s2 = 1; s2 < 16; s2 <<= 1) {
        int o = __shfl(hv, (lane - 4 * s2) & 63, 64);
        if (g >= s2) hv = max(hv, o);
    }
    int hdv = (hv > 0) ? hv - 1 : 0;
    bool complete = last_ex && (hv > 0);            // run fully inside this tile

    // per-edge state sources
    const unsigned short* sp = nullptr;
    const unsigned short* vp = nullptr;
    const float* eu = nullptr;
    unsigned short pf_s = 0, pf_v0 = 0, pf_v1 = 0, pf_v2 = 0;
    if constexpr (VZ) {
        eu = embup + (size_t)spec[srcn] * 32;       // 10-row L1 table
    } else {
        const unsigned short* row = pk + (size_t)srcn * 128;   // packed 256B row
        sp = row + l;                                // su channel l + 4*c4
        vp = row + 32 + 3 * l;                       // vu channel l + 4*c4
        pf_s  = sp[0];
        pf_v0 = vp[0]; pf_v1 = vp[1]; pf_v2 = vp[2];
    }

    float vx = posf[dstn * 3 + 0] - posf[srcn * 3 + 0];
    float vy = posf[dstn * 3 + 1] - posf[srcn * 3 + 1];
    float vz = posf[dstn * 3 + 2] - posf[srcn * 3 + 2];
    if (flags[O_SHZ]) {                // shifts nonzero: rare fallback path
        int isb = flags[O_FLAG];
        int e = eidA[i];
        vx += ldi(shifts, e * 3 + 0, isb);
        vy += ldi(shifts, e * 3 + 1, isb);
        vz += ldi(shifts, e * 3 + 2, isb);
    }
    float r2 = vx * vx + vy * vy + vz * vz;
    float r = sqrtf(r2);
    float rs = fmaxf(r, 1e-9f);
    float inv = 1.0f / rs;
    float Yx = vx * inv, Yy = vy * inv, Yz = vz * inv;

    // table coordinates: r in [0,5) -> k0 in [0,510], frac f
    float tpos = r * ((float)(NT_ - 1) / 5.0f);
    int k0 = min((int)tpos, NT_ - 2);
    float f = tpos - (float)k0;
    const float* t0 = tab + ((size_t)layer * NT_ + k0) * 256;   // 32 ch * 8 floats
    const float* t1 = t0 + 256;

    float* Sd = S + (size_t)dstn * 32;
    float* Vd = V + (size_t)dstn * 96;

    if constexpr (VZ) {
        // ---- layer-0 path: ss from L1 table, v=0 => only w0,w1 matter ----
        #pragma unroll 1
        for (int c4 = 0; c4 < 8; c4++) {
            const int c = 4 * c4 + l;
            float ss = eu[c];
            float2 wa2 = *(const float2*)(t0 + c * 8);
            float2 wb2 = *(const float2*)(t1 + c * 8);
            float w0 = wa2.x + f * (wb2.x - wa2.x);
            float w1 = wa2.y + f * (wb2.y - wa2.y);
            float ms = (w0 * ss) * scale;
            float w1s = (w1 * ss) * scale;
            float mx = w1s * Yx;
            float my = w1s * Yy;
            float mz = w1s * Yz;
            ms = segsum16(ms, lane, g, hdv);
            mx = segsum16(mx, lane, g, hdv);
            my = segsum16(my, lane, g, hdv);
            mz = segsum16(mz, lane, g, hdv);
            if (last_wt) {
                if (complete) {
                    Sd[c] = ms;
                    Vd[c * 3 + 0] = mx;
                    Vd[c * 3 + 1] = my;
                    Vd[c * 3 + 2] = mz;
                } else {
                    atomicAdd(Sd + c, ms);
                    atomicAdd(Vd + c * 3 + 0, mx);
                    atomicAdd(Vd + c * 3 + 1, my);
                    atomicAdd(Vd + c * 3 + 2, mz);
                }
            }
        }
    } else {
        // ---- full path (layer 1): r10-proven rolling-prefetch schedule ----
        float4 pf_wa = *(const float4*)(t0 + l * 8);
        float  pf_wa4 = (t0 + l * 8)[4];
        float4 pf_wb = *(const float4*)(t1 + l * 8);
        float  pf_wb4 = (t1 + l * 8)[4];

        #pragma unroll 1
        for (int c4 = 0; c4 < 8; c4++) {
            float ss  = b2f(pf_s);
            float vvx = b2f(pf_v0);
            float vvy = b2f(pf_v1);
            float vvz = b2f(pf_v2);
            float4 wa = pf_wa; float wa4 = pf_wa4;
            float4 wb = pf_wb; float wb4 = pf_wb4;

            // prefetch next chunk (states + table); c4=7 prefetch lands in-arena
            pf_s  = sp[4 * c4 + 4];
            pf_v0 = vp[12 * c4 + 12];
            pf_v1 = vp[12 * c4 + 13];
            pf_v2 = vp[12 * c4 + 14];
            int noff = (4 * c4 + 4 + l) * 8;
            pf_wa = *(const float4*)(t0 + noff);
            pf_wa4 = (t0 + noff)[4];
            pf_wb = *(const float4*)(t1 + noff);
            pf_wb4 = (t1 + noff)[4];

            float w0 = wa.x + f * (wb.x - wa.x);
            float w1 = wa.y + f * (wb.y - wa.y);
            float w2 = wa.z + f * (wb.z - wa.z);
            float w3 = wa.w + f * (wb.w - wa.w);
            float w4 = wa4 + f * (wb4 - wa4);

            const int c = 4 * c4 + l;
            float dt = vvx * Yx + vvy * Yy + vvz * Yz;
            float cx = vvy * Yz - vvz * Yy;
            float cy = vvz * Yx - vvx * Yz;
            float cz = vvx * Yy - vvy * Yx;
            float ms = (w0 * ss + w3 * dt) * scale;
            float mx = (w1 * ss * Yx + w2 * vvx + w4 * cx) * scale;
            float my = (w1 * ss * Yy + w2 * vvy + w4 * cy) * scale;
            float mz = (w1 * ss * Yz + w2 * vvz + w4 * cz) * scale;

            ms = segsum16(ms, lane, g, hdv);
            mx = segsum16(mx, lane, g, hdv);
            my = segsum16(my, lane, g, hdv);
            mz = segsum16(mz, lane, g, hdv);
            if (last_wt) {
                if (complete) {
                    Sd[c] = ms;
                    Vd[c * 3 + 0] = mx;
                    Vd[c * 3 + 1] = my;
                    Vd[c * 3 + 2] = mz;
                } else {
                    atomicAdd(Sd + c, ms);
                    atomicAdd(Vd + c * 3 + 0, mx);
                    atomicAdd(Vd + c * 3 + 1, my);
                    atomicAdd(Vd + c * 3 + 2, mz);
                }
            }
        }
    }
}

// ---- per-node post: out/skip/product/linear, writes invariants + new s,v in-place.
// When fuse!=0 also computes next layer's "up" into the PACKED pk row. ----
__global__ __launch_bounds__(256) void post_kernel(const float* __restrict__ Wc,
                                                   const float* __restrict__ Sb,
                                                   const float* __restrict__ Vb,
                                                   float* __restrict__ s,
                                                   bf16* __restrict__ vbst,
                                                   const int* __restrict__ spec,
                                                   float* __restrict__ out,
                                                   unsigned short* __restrict__ pk,
                                                   int fuse, int layer) {
    __shared__ float A_s[8][32];
    __shared__ float A_v[8][96];
    __shared__ float B_s[8][32];
    __shared__ float B_v[8][96];
    int tid = threadIdx.x;
    int nl = tid >> 5, d = tid & 31;
    int n = blockIdx.x * 8 + nl;
    A_s[nl][d]      = Sb[n * 32 + d];
    A_v[nl][d]      = Vb[n * 96 + d];
    A_v[nl][d + 32] = Vb[n * 96 + d + 32];
    A_v[nl][d + 64] = Vb[n * 96 + d + 64];
    B_s[nl][d]      = s[n * 32 + d];
    B_v[nl][d]      = (float)vbst[n * 96 + d];
    B_v[nl][d + 32] = (float)vbst[n * 96 + d + 32];
    B_v[nl][d + 64] = (float)vbst[n * 96 + d + 64];
    __syncthreads();

    int z = spec[n];
    const float* wos = Wc + OFF_OUTS + layer * 1024;
    const float* wov = Wc + OFF_OUTV + layer * 1024;
    const float* wss = Wc + OFF_SCS + (layer * Z_ + z) * 1024;
    const float* wsv = Wc + OFF_SCV + (layer * Z_ + z) * 1024;
    float s2 = 0.f, v20 = 0.f, v21 = 0.f, v22 = 0.f;
    float scs = 0.f, scv0 = 0.f, scv1 = 0.f, scv2 = 0.f;
    #pragma unroll 8
    for (int c = 0; c < 32; c++) {
        float wo = wos[c * 32 + d], wv = wov[c * 32 + d];
        float wa = wss[c * 32 + d], wb = wsv[c * 32 + d];
        s2  += A_s[nl][c] * wo;
        v20 += A_v[nl][c * 3 + 0] * wv;
        v21 += A_v[nl][c * 3 + 1] * wv;
        v22 += A_v[nl][c * 3 + 2] * wv;
        scs  += B_s[nl][c] * wa;
        scv0 += B_v[nl][c * 3 + 0] * wb;
        scv1 += B_v[nl][c * 3 + 1] * wb;
        scv2 += B_v[nl][c * 3 + 2] * wb;
    }
    const float* wp = Wc + OFF_WP + (layer * Z_ + z) * 160;
    float we0 = wp[d], we1 = wp[32 + d], we2 = wp[64 + d], we3 = wp[96 + d], we4 = wp[128 + d];
    float ps = we0 * s2 + we1 * s2 * s2 + we2 * (v20 * v20 + v21 * v21 + v22 * v22);
    float pv0 = we3 * v20 + we4 * s2 * v20;
    float pv1 = we3 * v21 + we4 * s2 * v21;
    float pv2 = we3 * v22 + we4 * s2 * v22;
    __syncthreads();
    A_s[nl][d] = ps;
    A_v[nl][d * 3 + 0] = pv0;
    A_v[nl][d * 3 + 1] = pv1;
    A_v[nl][d * 3 + 2] = pv2;
    __syncthreads();
    const float* wls = Wc + OFF_LINS + layer * 1024;
    const float* wlv = Wc + OFF_LINV + layer * 1024;
    float sn = scs, vn0 = scv0, vn1 = scv1, vn2 = scv2;
    #pragma unroll 8
    for (int c = 0; c < 32; c++) {
        float wl = wls[c * 32 + d], w2_ = wlv[c * 32 + d];
        sn  += A_s[nl][c] * wl;
        vn0 += A_v[nl][c * 3 + 0] * w2_;
        vn1 += A_v[nl][c * 3 + 1] * w2_;
        vn2 += A_v[nl][c * 3 + 2] * w2_;
    }
    s[n * 32 + d] = sn;
    out[(size_t)n * 64 + layer * 32 + d] = sn;   // fp32 output (verified round 5)
    vbst[n * 96 + d * 3 + 0] = __float2bfloat16(vn0);
    vbst[n * 96 + d * 3 + 1] = __float2bfloat16(vn1);
    vbst[n * 96 + d * 3 + 2] = __float2bfloat16(vn2);

    if (fuse) {
        __syncthreads();
        B_s[nl][d]         = sn;
        B_v[nl][d * 3 + 0] = vn0;
        B_v[nl][d * 3 + 1] = vn1;
        B_v[nl][d * 3 + 2] = vn2;
        __syncthreads();
        const float* wus = Wc + OFF_UPS + (layer + 1) * 1024;
        const float* wuv = Wc + OFF_UPV + (layer + 1) * 1024;
        float a0 = 0.f, b0 = 0.f, b1 = 0.f, b2 = 0.f;
        #pragma unroll 8
        for (int c = 0; c < 32; c++) {
            float wS = wus[c * 32 + d], wV = wuv[c * 32 + d];
            a0 += B_s[nl][c] * wS;
            b0 += B_v[nl][c * 3 + 0] * wV;
            b1 += B_v[nl][c * 3 + 1] * wV;
            b2 += B_v[nl][c * 3 + 2] * wV;
        }
        unsigned short* row = pk + (size_t)n * 128;
        row[d] = __bfloat16_as_ushort(__float2bfloat16(a0));
        row[32 + d * 3 + 0] = __bfloat16_as_ushort(__float2bfloat16(b0));
        row[32 + d * 3 + 1] = __bfloat16_as_ushort(__float2bfloat16(b1));
        row[32 + d * 3 + 2] = __bfloat16_as_ushort(__float2bfloat16(b2));
    }
}

// Host-side: resolve input pointers by element count (robust to harness input
// ordering). Greedy first-unused match preserves relative order within equal
// sizes, so if the harness order == reference dict order this is the identity.
static void resolve_inputs(const int* in_sizes, int n_in, int idx[17]) {
    const int want[17] = {150000, 500000, 2400000, 320, 2048, 2048, 1024, 8192,
                          20480, 2048, 2048, 20480, 20480, 3200, 2048, 2048, 1600000};
    for (int k = 0; k < 17; k++) idx[k] = k;   // default identity
    if (!in_sizes || n_in < 17) return;
    bool used[64];
    for (int i = 0; i < 64; i++) used[i] = false;
    int tmp[17];
    for (int k = 0; k < 17; k++) {
        int found = -1;
        for (int i = 0; i < n_in && i < 64; i++) {
            if (!used[i] && in_sizes[i] == want[k]) { found = i; break; }
        }
        if (found < 0) return;               // sizes don't match expectation: keep identity
        used[found] = true;
        tmp[k] = found;
    }
    for (int k = 0; k < 17; k++) idx[k] = tmp[k];
}

extern "C" void kernel_launch(void* const* d_in, const int* in_sizes, int n_in,
                              void* d_out, int out_size, void* d_ws, size_t ws_size,
                              hipStream_t stream) {
    (void)out_size; (void)ws_size;
    int idx[17];
    resolve_inputs(in_sizes, n_in, idx);

    const void* pos    = d_in[idx[0]];
    const void* attrs  = d_in[idx[1]];
    const void* shifts = d_in[idx[2]];
    const int*  ei     = (const int*)d_in[idx[16]];
    float* out = (float*)d_out;

    int*   I = (int*)d_ws;
    float* W = (float*)d_ws;

    hipMemsetAsync(I, 0, 64 * sizeof(int), stream);                             // cnt + flags
    hipMemsetAsync(I + O_ROWP, 0, 50048 * sizeof(int), stream);                 // degrees
    hipMemsetAsync(W + O_VB, 0, (size_t)N_ * C_ * 3 * sizeof(bf16), stream);    // v state = 0

    detect_kernel<<<1, 256, 0, stream>>>((const unsigned*)attrs, I + O_FLAG);
    shiftchk_kernel<<<2048, 256, 0, stream>>>((const unsigned*)shifts, I + O_FLAG, I + O_SHZ);

    ConvArgs ca;
    for (int k = 0; k < 13; k++) ca.p[k] = d_in[idx[3 + k]];
    convert_kernel<<<(W_TOTAL + 255) / 256, 256, 0, stream>>>(ca, I + O_FLAG, W + O_W);
    posconv_kernel<<<(N_ * 3 + 255) / 256, 256, 0, stream>>>(pos, I + O_FLAG, W + O_POSF);
    spec_kernel<<<(N_ + 255) / 256, 256, 0, stream>>>(attrs, I + O_FLAG, I + O_SPEC);
    embup_kernel<<<1, 320, 0, stream>>>(W + O_W, W + O_EMBU);
    sinit_kernel<<<(N_ * C_) / 256, 256, 0, stream>>>(W + O_W, I + O_SPEC, W + O_S);

    // radial w-table (both layers; needs converted weights)
    tab_kernel<<<2 * NT_, 256, 0, stream>>>(W + O_W, W + O_TAB);

    // one-time dst-sorted active-edge list (counting sort; graph static across layers)
    deg_kernel<<<E_ / 256, 256, 0, stream>>>(ei, W + O_POSF, shifts, I, I + O_ROWP);
    scanA_kernel<<<NSB_, 256, 0, stream>>>(I + O_ROWP, I + O_BSUM);
    scanB_kernel<<<1, 64, 0, stream>>>(I + O_BSUM, I + O_CNT);
    scanC_kernel<<<NSB_, 256, 0, stream>>>(I + O_ROWP, I + O_BSUM);
    scatter_kernel<<<E_ / 256, 256, 0, stream>>>(ei, W + O_POSF, shifts, I,
                                                 I + O_ROWP, (unsigned*)(I + O_SD),
                                                 I + O_EID2);

    for (int l = 0; l < 2; l++) {
        hipMemsetAsync(W + O_SS, 0, (size_t)N_ * C_ * 4 * sizeof(float), stream);  // SS+VV
        if (l == 0)
            msg_kernel<1><<<(E_ + 63) / 64, 256, 0, stream>>>(
                (const unsigned*)(I + O_SD), I + O_EID2, I + O_CNT,
                W + O_POSF, shifts, I, W + O_TAB,
                (const unsigned short*)(W + O_PK),
                I + O_SPEC, W + O_EMBU, W + O_SS, W + O_VV, l);
        else
            msg_kernel<0><<<(E_ + 63) / 64, 256, 0, stream>>>(
                (const unsigned*)(I + O_SD), I + O_EID2, I + O_CNT,
                W + O_POSF, shifts, I, W + O_TAB,
                (const unsigned short*)(W + O_PK),
                I + O_SPEC, W + O_EMBU, W + O_SS, W + O_VV, l);
        post_kernel<<<N_ / 8, 256, 0, stream>>>(W + O_W, W + O_SS, W + O_VV,
                                                W + O_S, (bf16*)(W + O_VB),
                                                I + O_SPEC, out,
                                                (unsigned short*)(W + O_PK),
                                                (l == 0) ? 1 : 0, l);
    }
}